// Round 1
// baseline (7909.203 us; speedup 1.0000x reference)
//
#include <hip/hip_runtime.h>
#include <hip/hip_bf16.h>
#include <math.h>

constexpr int N    = 50000;
constexpr int NE   = 500000;
constexpr int IN   = 128;
constexpr int H    = 8;
constexpr int D    = 16;
constexpr int DSEM = 4;
constexpr int KS   = 21;
constexpr float CLAMP = 5.0f;

// ---------------------------------------------------------------------------
// K1: fused QKV projection + RoPE.  16 nodes per 256-thread block.
// ---------------------------------------------------------------------------
constexpr int NPB = 16;          // nodes per block
constexpr int XPAD = IN + 4;     // padded LDS stride (float4-aligned, bank-spread)

__global__ __launch_bounds__(256) void qkv_rope_kernel(
    const float* __restrict__ x, const float* __restrict__ rrwp,
    const float* __restrict__ Qw, const float* __restrict__ Qb,
    const float* __restrict__ Kw, const float* __restrict__ Kb,
    const float* __restrict__ Vw, const float* __restrict__ Vb,
    const float* __restrict__ Wang,
    float* __restrict__ Qh, float* __restrict__ Kh, float* __restrict__ Vh)
{
    __shared__ float sx[NPB][XPAD];
    __shared__ float sout[NPB][384];
    __shared__ float srr[NPB][KS];
    __shared__ float sc[NPB][48];
    __shared__ float ss[NPB][48];

    const int nb = blockIdx.x * NPB;
    const int t  = threadIdx.x;

    // stage x rows + rrwp rows
    for (int i = t; i < NPB * IN; i += 256) {
        int nl = i / IN, k = i % IN;
        int n = nb + nl;
        sx[nl][k] = (n < N) ? x[(size_t)n * IN + k] : 0.0f;
    }
    for (int i = t; i < NPB * KS; i += 256) {
        int nl = i / KS, k = i % KS;
        int n = nb + nl;
        srr[nl][k] = (n < N) ? rrwp[(size_t)n * KS + k] : 0.0f;
    }
    __syncthreads();

    // 384 outputs x NPB nodes = 6144 dots; 16 lanes share one weight row
    for (int rep = 0; rep < (384 * NPB) / 256; rep++) {
        int idx = rep * 256 + t;
        int o  = idx / NPB;
        int nl = idx % NPB;
        const float* w;
        float b;
        if (o < 128)      { w = Qw + (size_t)o * IN;         b = Qb[o];       }
        else if (o < 256) { w = Kw + (size_t)(o - 128) * IN; b = Kb[o - 128]; }
        else              { w = Vw + (size_t)(o - 256) * IN; b = Vb[o - 256]; }
        const float4* w4 = (const float4*)w;
        float acc0 = 0.0f, acc1 = 0.0f;
        #pragma unroll
        for (int k = 0; k < 16; k++) {
            float4 wv0 = w4[k];
            float4 wv1 = w4[k + 16];
            acc0 = fmaf(sx[nl][4*k+0],      wv0.x, acc0);
            acc0 = fmaf(sx[nl][4*k+1],      wv0.y, acc0);
            acc0 = fmaf(sx[nl][4*k+2],      wv0.z, acc0);
            acc0 = fmaf(sx[nl][4*k+3],      wv0.w, acc0);
            acc1 = fmaf(sx[nl][64+4*k+0],   wv1.x, acc1);
            acc1 = fmaf(sx[nl][64+4*k+1],   wv1.y, acc1);
            acc1 = fmaf(sx[nl][64+4*k+2],   wv1.z, acc1);
            acc1 = fmaf(sx[nl][64+4*k+3],   wv1.w, acc1);
        }
        sout[nl][o] = b + acc0 + acc1;
    }
    __syncthreads();

    // angles: NPB * H * 6 = 768
    for (int i = t; i < NPB * 48; i += 256) {
        int nl = i / 48, a = i % 48;
        int h = a / 6, r = a % 6;
        float acc = 0.0f;
        #pragma unroll
        for (int k = 0; k < KS; k++)
            acc = fmaf(srr[nl][k], Wang[(size_t)(h * KS + k) * 6 + r], acc);
        float sv, cv;
        sincosf(acc, &sv, &cv);
        sc[nl][a] = cv;
        ss[nl][a] = sv;
    }
    __syncthreads();

    // rotate + write out
    for (int i = t; i < NPB * 384; i += 256) {
        int nl = i / 384, o = i % 384;
        int n = nb + nl;
        if (n >= N) continue;
        int mat = o >> 7;           // 0=Q 1=K 2=V
        int oo  = o & 127;
        int h = oo >> 4, d = oo & 15;
        float val;
        if (mat == 2 || d < DSEM) {
            val = sout[nl][o];
        } else {
            int i2 = (d - DSEM) >> 1;
            float c  = sc[nl][h * 6 + i2];
            float s2 = ss[nl][h * 6 + i2];
            int base = (mat << 7) + h * 16 + DSEM + 2 * i2;
            float xe = sout[nl][base];
            float xo = sout[nl][base + 1];
            val = ((d & 1) == 0) ? (xe * c - xo * s2) : (xe * s2 + xo * c);
        }
        float* dp = (mat == 0) ? Qh : (mat == 1) ? Kh : Vh;
        dp[(size_t)n * 128 + oo] = val;
    }
}

// ---------------------------------------------------------------------------
// K2: per-edge fused projection + logit + exp + den-accum + wE.
// Thread per edge; edge row held in 32 float4 registers; weight rows are
// wave-uniform -> scalar-load streams.
// ---------------------------------------------------------------------------
__global__ __launch_bounds__(256, 2) void edge_main_kernel(
    const float* __restrict__ edge_attr,
    const int* __restrict__ srcI, const int* __restrict__ dstI,
    const float* __restrict__ Qh, const float* __restrict__ Kh,
    const float* __restrict__ Ew, const float* __restrict__ Eb,
    const float* __restrict__ wew, const float* __restrict__ web,
    float* __restrict__ wE, float* __restrict__ exOut, float* __restrict__ den)
{
    const int e = blockIdx.x * 256 + threadIdx.x;
    if (e >= NE) return;

    float4 a[32];
    {
        const float4* ar = (const float4*)(edge_attr + (size_t)e * 128);
        #pragma unroll
        for (int k = 0; k < 32; k++) a[k] = ar[k];
    }
    const int s  = srcI[e];
    const int dd = dstI[e];
    const float4* Ks4 = (const float4*)(Kh + (size_t)s * 128);
    const float4* Qd4 = (const float4*)(Qh + (size_t)dd * 128);
    float* wEr = wE + (size_t)e * 128;

    const float inv_s4  = 0.5f;
    const float inv_s12 = 0.28867513459481288f;  // 1/sqrt(12)

    #pragma unroll 1
    for (int h = 0; h < H; h++) {
        float4 kf[4], qf[4];
        #pragma unroll
        for (int j = 0; j < 4; j++) { kf[j] = Ks4[h * 4 + j]; qf[j] = Qd4[h * 4 + j]; }

        // e_bias (two accumulator chains)
        float eb;
        {
            const float4* w4 = (const float4*)(wew + (size_t)h * 128);
            float a0 = 0.0f, a1 = 0.0f;
            #pragma unroll
            for (int k = 0; k < 16; k++) {
                float4 w0 = w4[k], w1 = w4[k + 16];
                a0 = fmaf(a[k].x, w0.x, a0); a0 = fmaf(a[k].y, w0.y, a0);
                a0 = fmaf(a[k].z, w0.z, a0); a0 = fmaf(a[k].w, w0.w, a0);
                a1 = fmaf(a[k+16].x, w1.x, a1); a1 = fmaf(a[k+16].y, w1.y, a1);
                a1 = fmaf(a[k+16].z, w1.z, a1); a1 = fmaf(a[k+16].w, w1.w, a1);
            }
            eb = web[h] + a0 + a1;
        }

        // sem + stl
        float sem = kf[0].x*qf[0].x + kf[0].y*qf[0].y + kf[0].z*qf[0].z + kf[0].w*qf[0].w;
        float stl = 0.0f;
        #pragma unroll
        for (int j = 1; j < 4; j++)
            stl += kf[j].x*qf[j].x + kf[j].y*qf[j].y + kf[j].z*qf[j].z + kf[j].w*qf[j].w;

        float logit = sem * inv_s4 + stl * inv_s12 + eb;
        logit = fminf(fmaxf(logit, -CLAMP), CLAMP);
        float ex = __expf(logit);
        exOut[(size_t)e * H + h] = ex;
        atomicAdd(&den[dd * H + h], ex);

        // wE: 16 d-values, 2 dots (A-mult, B-add) each
        #pragma unroll 1
        for (int jq = 0; jq < 4; jq++) {
            float4 kq = kf[jq], qq = qf[jq];
            float kpq[4] = { kq.x + qq.x, kq.y + qq.y, kq.z + qq.z, kq.w + qq.w };
            float out[4];
            #pragma unroll
            for (int jj = 0; jj < 4; jj++) {
                int d = jq * 4 + jj;
                const float4* wa = (const float4*)(Ew + (size_t)(h * 32 + d) * 128);
                const float4* wb = (const float4*)(Ew + (size_t)(h * 32 + 16 + d) * 128);
                float accA = Eb[h * 32 + d];
                float accB = Eb[h * 32 + 16 + d];
                #pragma unroll
                for (int k = 0; k < 32; k++) {
                    float4 w1 = wa[k], w2 = wb[k];
                    accA = fmaf(a[k].x, w1.x, accA); accA = fmaf(a[k].y, w1.y, accA);
                    accA = fmaf(a[k].z, w1.z, accA); accA = fmaf(a[k].w, w1.w, accA);
                    accB = fmaf(a[k].x, w2.x, accB); accB = fmaf(a[k].y, w2.y, accB);
                    accB = fmaf(a[k].z, w2.z, accB); accB = fmaf(a[k].w, w2.w, accB);
                }
                float xv = kpq[jj] * accA;
                out[jj] = copysignf(sqrtf(fabsf(xv)), xv) + accB;
            }
            ((float4*)wEr)[h * 4 + jq] = make_float4(out[0], out[1], out[2], out[3]);
        }
    }
}

// ---------------------------------------------------------------------------
// K3: attn normalize + weighted V scatter (atomicAdd).
// Thread per (edge, head).
// ---------------------------------------------------------------------------
__global__ __launch_bounds__(256) void edge_msg_kernel(
    const int* __restrict__ srcI, const int* __restrict__ dstI,
    const float* __restrict__ Vh, const float* __restrict__ exOut,
    const float* __restrict__ den, float* __restrict__ wV)
{
    const int gid = blockIdx.x * 256 + threadIdx.x;
    if (gid >= NE * H) return;
    const int e = gid >> 3;
    const int h = gid & 7;
    const int s  = srcI[e];
    const int dd = dstI[e];
    const float ex = exOut[gid];
    const float attn = ex / (den[dd * H + h] + 1e-16f);

    const float4* V4 = (const float4*)(Vh + (size_t)s * 128 + h * 16);
    float* out = wV + (size_t)dd * 128 + h * 16;
    #pragma unroll
    for (int j = 0; j < 4; j++) {
        float4 v = V4[j];
        atomicAdd(out + 4 * j + 0, v.x * attn);
        atomicAdd(out + 4 * j + 1, v.y * attn);
        atomicAdd(out + 4 * j + 2, v.z * attn);
        atomicAdd(out + 4 * j + 3, v.w * attn);
    }
}

// ---------------------------------------------------------------------------
extern "C" void kernel_launch(void* const* d_in, const int* in_sizes, int n_in,
                              void* d_out, int out_size, void* d_ws, size_t ws_size,
                              hipStream_t stream)
{
    const float* x         = (const float*)d_in[0];
    const int*   edge_idx  = (const int*)d_in[1];
    const float* rrwp      = (const float*)d_in[2];
    const float* edge_attr = (const float*)d_in[3];
    const float* Qw        = (const float*)d_in[4];
    const float* Qb        = (const float*)d_in[5];
    const float* Kw        = (const float*)d_in[6];
    const float* Kb        = (const float*)d_in[7];
    const float* Vw        = (const float*)d_in[8];
    const float* Vb        = (const float*)d_in[9];
    const float* Ew        = (const float*)d_in[10];
    const float* Eb        = (const float*)d_in[11];
    const float* wew       = (const float*)d_in[12];
    const float* web       = (const float*)d_in[13];
    const float* Wang      = (const float*)d_in[14];

    const int* srcI = edge_idx;         // edge_index[0]
    const int* dstI = edge_idx + NE;    // edge_index[1]

    float* wV = (float*)d_out;                       // N * 128
    float* wE = wV + (size_t)N * 128;                // NE * 128

    float* ws  = (float*)d_ws;
    float* Qh  = ws;                                 // N * 128
    float* Kh  = Qh + (size_t)N * 128;               // N * 128
    float* Vh  = Kh + (size_t)N * 128;               // N * 128
    float* exO = Vh + (size_t)N * 128;               // NE * H
    float* den = exO + (size_t)NE * H;               // N * H

    hipMemsetAsync(den, 0, (size_t)N * H * sizeof(float), stream);
    hipMemsetAsync(wV, 0, (size_t)N * 128 * sizeof(float), stream);

    qkv_rope_kernel<<<(N + NPB - 1) / NPB, 256, 0, stream>>>(
        x, rrwp, Qw, Qb, Kw, Kb, Vw, Vb, Wang, Qh, Kh, Vh);

    edge_main_kernel<<<(NE + 255) / 256, 256, 0, stream>>>(
        edge_attr, srcI, dstI, Qh, Kh, Ew, Eb, wew, web, wE, exO, den);

    edge_msg_kernel<<<((size_t)NE * H + 255) / 256, 256, 0, stream>>>(
        srcI, dstI, Vh, exO, den, wV);
}

// Round 2
// 1950.577 us; speedup vs baseline: 4.0548x; 4.0548x over previous
//
#include <hip/hip_runtime.h>
#include <hip/hip_bf16.h>
#include <math.h>

constexpr int N    = 50000;
constexpr int NE   = 500000;
constexpr int IN   = 128;
constexpr int H    = 8;
constexpr int D    = 16;
constexpr int DSEM = 4;
constexpr int KS   = 21;
constexpr float CLAMP = 5.0f;

// ---------------------------------------------------------------------------
// K1: fused QKV projection + RoPE.  16 nodes per 256-thread block. (unchanged)
// ---------------------------------------------------------------------------
constexpr int NPB = 16;
constexpr int XPAD = IN + 4;

__global__ __launch_bounds__(256) void qkv_rope_kernel(
    const float* __restrict__ x, const float* __restrict__ rrwp,
    const float* __restrict__ Qw, const float* __restrict__ Qb,
    const float* __restrict__ Kw, const float* __restrict__ Kb,
    const float* __restrict__ Vw, const float* __restrict__ Vb,
    const float* __restrict__ Wang,
    float* __restrict__ Qh, float* __restrict__ Kh, float* __restrict__ Vh)
{
    __shared__ float sx[NPB][XPAD];
    __shared__ float sout[NPB][384];
    __shared__ float srr[NPB][KS];
    __shared__ float sc[NPB][48];
    __shared__ float ss[NPB][48];

    const int nb = blockIdx.x * NPB;
    const int t  = threadIdx.x;

    for (int i = t; i < NPB * IN; i += 256) {
        int nl = i / IN, k = i % IN;
        int n = nb + nl;
        sx[nl][k] = (n < N) ? x[(size_t)n * IN + k] : 0.0f;
    }
    for (int i = t; i < NPB * KS; i += 256) {
        int nl = i / KS, k = i % KS;
        int n = nb + nl;
        srr[nl][k] = (n < N) ? rrwp[(size_t)n * KS + k] : 0.0f;
    }
    __syncthreads();

    for (int rep = 0; rep < (384 * NPB) / 256; rep++) {
        int idx = rep * 256 + t;
        int o  = idx / NPB;
        int nl = idx % NPB;
        const float* w;
        float b;
        if (o < 128)      { w = Qw + (size_t)o * IN;         b = Qb[o];       }
        else if (o < 256) { w = Kw + (size_t)(o - 128) * IN; b = Kb[o - 128]; }
        else              { w = Vw + (size_t)(o - 256) * IN; b = Vb[o - 256]; }
        const float4* w4 = (const float4*)w;
        float acc0 = 0.0f, acc1 = 0.0f;
        #pragma unroll
        for (int k = 0; k < 16; k++) {
            float4 wv0 = w4[k];
            float4 wv1 = w4[k + 16];
            acc0 = fmaf(sx[nl][4*k+0],      wv0.x, acc0);
            acc0 = fmaf(sx[nl][4*k+1],      wv0.y, acc0);
            acc0 = fmaf(sx[nl][4*k+2],      wv0.z, acc0);
            acc0 = fmaf(sx[nl][4*k+3],      wv0.w, acc0);
            acc1 = fmaf(sx[nl][64+4*k+0],   wv1.x, acc1);
            acc1 = fmaf(sx[nl][64+4*k+1],   wv1.y, acc1);
            acc1 = fmaf(sx[nl][64+4*k+2],   wv1.z, acc1);
            acc1 = fmaf(sx[nl][64+4*k+3],   wv1.w, acc1);
        }
        sout[nl][o] = b + acc0 + acc1;
    }
    __syncthreads();

    for (int i = t; i < NPB * 48; i += 256) {
        int nl = i / 48, a = i % 48;
        int h = a / 6, r = a % 6;
        float acc = 0.0f;
        #pragma unroll
        for (int k = 0; k < KS; k++)
            acc = fmaf(srr[nl][k], Wang[(size_t)(h * KS + k) * 6 + r], acc);
        float sv, cv;
        sincosf(acc, &sv, &cv);
        sc[nl][a] = cv;
        ss[nl][a] = sv;
    }
    __syncthreads();

    for (int i = t; i < NPB * 384; i += 256) {
        int nl = i / 384, o = i % 384;
        int n = nb + nl;
        if (n >= N) continue;
        int mat = o >> 7;
        int oo  = o & 127;
        int h = oo >> 4, d = oo & 15;
        float val;
        if (mat == 2 || d < DSEM) {
            val = sout[nl][o];
        } else {
            int i2 = (d - DSEM) >> 1;
            float c  = sc[nl][h * 6 + i2];
            float s2 = ss[nl][h * 6 + i2];
            int base = (mat << 7) + h * 16 + DSEM + 2 * i2;
            float xe = sout[nl][base];
            float xo = sout[nl][base + 1];
            val = ((d & 1) == 0) ? (xe * c - xo * s2) : (xe * s2 + xo * c);
        }
        float* dp = (mat == 0) ? Qh : (mat == 1) ? Kh : Vh;
        dp[(size_t)n * 128 + oo] = val;
    }
}

// ---------------------------------------------------------------------------
// K2: LDS-tiled fp32 GEMM (E_proj, 64 edges x 256 outputs per block) with
// fused e_bias, logit/exp, and wE epilogue.  No per-thread edge-row array ->
// no spills.
// ---------------------------------------------------------------------------
constexpr int BE   = 64;
constexpr int SA_S = 36;    // sA stride (64 rows x 36)
constexpr int SW_S = 268;   // sW stride (32 rows x 268), 4-aligned
constexpr int SO_S = 260;   // sOut stride (64 rows x 260), 4-aligned

__global__ __launch_bounds__(256, 2) void edge_gemm_kernel(
    const float* __restrict__ edge_attr,
    const int* __restrict__ srcI, const int* __restrict__ dstI,
    const float* __restrict__ Qh, const float* __restrict__ Kh,
    const float* __restrict__ Ew, const float* __restrict__ Eb,
    const float* __restrict__ wew, const float* __restrict__ web,
    float* __restrict__ wE, float* __restrict__ exOut)
{
    __shared__ float smem[16640 + 512];        // 68.6 KB -> 2 blocks/CU
    float* sA    = smem;                        // [64][36]   (GEMM phase)
    float* sW    = smem + 2304;                 // [32][268]
    float* sWe   = smem + 2304 + 8576;          // [8][132]  ends @11936
    float* sOut  = smem;                        // [64][260]  (epilogue phase)
    float* sBias = smem + 16640;                // [64][8]    (never overlapped)

    const int t   = threadIdx.x;
    const int tx  = t & 15;      // output group: o = tx*16 .. tx*16+15
    const int ty  = t >> 4;      // edge group:   e = 4*ty .. 4*ty+3
    const int eb0 = blockIdx.x * BE;

    // stage wew once (full 128-k rows, 8 heads)
    for (int i = t; i < 8 * 128; i += 256) {
        int h = i >> 7, k = i & 127;
        sWe[h * 132 + k] = wew[h * 128 + k];
    }

    float acc[4][16];
    #pragma unroll
    for (int j = 0; j < 4; j++)
        #pragma unroll
        for (int c = 0; c < 16; c++) acc[j][c] = 0.0f;
    float eb_acc[2] = {0.0f, 0.0f};

    for (int kc = 0; kc < 128; kc += 32) {
        __syncthreads();
        // stage A chunk: 64 edges x 32 k
        for (int i = t; i < 64 * 32; i += 256) {
            int e = i >> 5, k = i & 31;
            int ge = eb0 + e;
            sA[e * SA_S + k] = (ge < NE) ? edge_attr[(size_t)ge * 128 + kc + k] : 0.0f;
        }
        // stage W chunk: 256 outputs x 32 k (transposed to k-major)
        for (int i = t; i < 256 * 8; i += 256) {
            int o = i >> 3, k4 = (i & 7) * 4;
            const float4 w = *(const float4*)(Ew + (size_t)o * 128 + kc + k4);
            sW[(k4 + 0) * SW_S + o] = w.x;
            sW[(k4 + 1) * SW_S + o] = w.y;
            sW[(k4 + 2) * SW_S + o] = w.z;
            sW[(k4 + 3) * SW_S + o] = w.w;
        }
        __syncthreads();

        // e_bias partials: 512 (e,h) pairs, 2 per thread
        #pragma unroll
        for (int r = 0; r < 2; r++) {
            int id = t * 2 + r;
            int e = id >> 3, h = id & 7;
            float s0 = 0.0f;
            #pragma unroll
            for (int k = 0; k < 32; k++)
                s0 = fmaf(sA[e * SA_S + k], sWe[h * 132 + kc + k], s0);
            eb_acc[r] += s0;
        }

        // GEMM: 4 edges x 16 outputs per thread
        #pragma unroll 2
        for (int kk = 0; kk < 32; kk++) {
            float a0 = sA[(4 * ty + 0) * SA_S + kk];
            float a1 = sA[(4 * ty + 1) * SA_S + kk];
            float a2 = sA[(4 * ty + 2) * SA_S + kk];
            float a3 = sA[(4 * ty + 3) * SA_S + kk];
            const float4* wr = (const float4*)(sW + kk * SW_S + tx * 16);
            #pragma unroll
            for (int u = 0; u < 4; u++) {
                float4 w = wr[u];
                acc[0][4*u+0] = fmaf(a0, w.x, acc[0][4*u+0]);
                acc[0][4*u+1] = fmaf(a0, w.y, acc[0][4*u+1]);
                acc[0][4*u+2] = fmaf(a0, w.z, acc[0][4*u+2]);
                acc[0][4*u+3] = fmaf(a0, w.w, acc[0][4*u+3]);
                acc[1][4*u+0] = fmaf(a1, w.x, acc[1][4*u+0]);
                acc[1][4*u+1] = fmaf(a1, w.y, acc[1][4*u+1]);
                acc[1][4*u+2] = fmaf(a1, w.z, acc[1][4*u+2]);
                acc[1][4*u+3] = fmaf(a1, w.w, acc[1][4*u+3]);
                acc[2][4*u+0] = fmaf(a2, w.x, acc[2][4*u+0]);
                acc[2][4*u+1] = fmaf(a2, w.y, acc[2][4*u+1]);
                acc[2][4*u+2] = fmaf(a2, w.z, acc[2][4*u+2]);
                acc[2][4*u+3] = fmaf(a2, w.w, acc[2][4*u+3]);
                acc[3][4*u+0] = fmaf(a3, w.x, acc[3][4*u+0]);
                acc[3][4*u+1] = fmaf(a3, w.y, acc[3][4*u+1]);
                acc[3][4*u+2] = fmaf(a3, w.z, acc[3][4*u+2]);
                acc[3][4*u+3] = fmaf(a3, w.w, acc[3][4*u+3]);
            }
        }
    }

    // finalize e_bias into sBias (region never overlaps sA/sW)
    #pragma unroll
    for (int r = 0; r < 2; r++) {
        int id = t * 2 + r;
        int e = id >> 3, h = id & 7;
        sBias[e * 8 + h] = eb_acc[r] + web[h];
    }
    __syncthreads();            // all GEMM/ebias LDS reads complete

    // write E_proj (+bias) fragments into sOut
    {
        float ebv[16];
        #pragma unroll
        for (int c = 0; c < 16; c++) ebv[c] = Eb[tx * 16 + c];
        #pragma unroll
        for (int j = 0; j < 4; j++) {
            float* row = sOut + (4 * ty + j) * SO_S + tx * 16;
            #pragma unroll
            for (int u = 0; u < 4; u++) {
                float4 v = make_float4(acc[j][4*u+0] + ebv[4*u+0],
                                       acc[j][4*u+1] + ebv[4*u+1],
                                       acc[j][4*u+2] + ebv[4*u+2],
                                       acc[j][4*u+3] + ebv[4*u+3]);
                *(float4*)(row + 4 * u) = v;
            }
        }
    }
    __syncthreads();

    // per-edge epilogue: 4 threads/edge, 2 heads each
    const int e_l = t >> 2;
    const int hp  = t & 3;
    const int ge  = eb0 + e_l;
    if (ge < NE) {
        const int s  = srcI[ge];
        const int dd = dstI[ge];
        const float4* K4 = (const float4*)(Kh + (size_t)s  * 128);
        const float4* Q4 = (const float4*)(Qh + (size_t)dd * 128);
        const float inv_s4  = 0.5f;
        const float inv_s12 = 0.28867513459481288f;
        #pragma unroll
        for (int hi = 0; hi < 2; hi++) {
            int hh = 2 * hp + hi;
            float4 kf[4], qf[4];
            #pragma unroll
            for (int j = 0; j < 4; j++) { kf[j] = K4[hh*4+j]; qf[j] = Q4[hh*4+j]; }
            float sem = kf[0].x*qf[0].x + kf[0].y*qf[0].y + kf[0].z*qf[0].z + kf[0].w*qf[0].w;
            float stl = 0.0f;
            #pragma unroll
            for (int j = 1; j < 4; j++)
                stl += kf[j].x*qf[j].x + kf[j].y*qf[j].y + kf[j].z*qf[j].z + kf[j].w*qf[j].w;
            float logit = sem * inv_s4 + stl * inv_s12 + sBias[e_l * 8 + hh];
            logit = fminf(fmaxf(logit, -CLAMP), CLAMP);
            float ex = __expf(logit);
            exOut[(size_t)ge * 8 + hh] = ex;
            const float* srow = sOut + e_l * SO_S + hh * 32;
            #pragma unroll
            for (int u = 0; u < 4; u++) {
                float4 A = *(const float4*)(srow + 4 * u);
                float4 B = *(const float4*)(srow + 16 + 4 * u);
                float4 kq = make_float4(kf[u].x + qf[u].x, kf[u].y + qf[u].y,
                                        kf[u].z + qf[u].z, kf[u].w + qf[u].w);
                float4 o;
                float v;
                v = kq.x * A.x; o.x = copysignf(sqrtf(fabsf(v)), v) + B.x;
                v = kq.y * A.y; o.y = copysignf(sqrtf(fabsf(v)), v) + B.y;
                v = kq.z * A.z; o.z = copysignf(sqrtf(fabsf(v)), v) + B.z;
                v = kq.w * A.w; o.w = copysignf(sqrtf(fabsf(v)), v) + B.w;
                *(float4*)(wE + (size_t)ge * 128 + hh * 16 + 4 * u) = o;
            }
        }
    }
}

// ---------------------------------------------------------------------------
// CSR build: count -> scan -> scatter
// ---------------------------------------------------------------------------
__global__ __launch_bounds__(256) void count_kernel(
    const int* __restrict__ dstI, int* __restrict__ cnt)
{
    int e = blockIdx.x * 256 + threadIdx.x;
    if (e < NE) atomicAdd(&cnt[dstI[e]], 1);
}

__global__ __launch_bounds__(1024) void scan_kernel(
    const int* __restrict__ cnt, int* __restrict__ rowstart)
{
    __shared__ int sbuf[1024];
    const int t = threadIdx.x;
    int carry = 0;
    for (int base = 0; base < N; base += 1024) {
        int i = base + t;
        int v = (i < N) ? cnt[i] : 0;
        sbuf[t] = v;
        __syncthreads();
        for (int off = 1; off < 1024; off <<= 1) {
            int x = sbuf[t];
            int y = (t >= off) ? sbuf[t - off] : 0;
            __syncthreads();
            sbuf[t] = x + y;
            __syncthreads();
        }
        int incl = sbuf[t];
        if (i < N) rowstart[i + 1] = carry + incl;
        carry += sbuf[1023];
        __syncthreads();
    }
    if (t == 0) rowstart[0] = 0;
}

__global__ __launch_bounds__(256) void scatter_kernel(
    const int* __restrict__ dstI, const int* __restrict__ rowstart,
    int* __restrict__ cursor, int* __restrict__ elist)
{
    int e = blockIdx.x * 256 + threadIdx.x;
    if (e >= NE) return;
    int d = dstI[e];
    int pos = atomicAdd(&cursor[d], 1);
    elist[rowstart[d] + pos] = e;
}

// ---------------------------------------------------------------------------
// K3': gather-based wV — one 128-thread group per dst, single pass
// wV[dd][o] = (sum_e ex[e][h] * V[src][o]) / (sum_e ex[e][h] + eps)
// ---------------------------------------------------------------------------
__global__ __launch_bounds__(256) void wv_kernel(
    const int* __restrict__ srcI, const int* __restrict__ elist,
    const int* __restrict__ rowstart, const float* __restrict__ Vh,
    const float* __restrict__ exOut, float* __restrict__ wV)
{
    const int dd = blockIdx.x * 2 + (threadIdx.x >> 7);
    const int o  = threadIdx.x & 127;
    if (dd >= N) return;
    const int h  = o >> 4;
    const int st = rowstart[dd];
    const int en = rowstart[dd + 1];
    float den = 0.0f, num = 0.0f;
    for (int i = st; i < en; i++) {
        int e = elist[i];
        float ex = exOut[(size_t)e * 8 + h];
        int s = srcI[e];
        num = fmaf(Vh[(size_t)s * 128 + o], ex, num);
        den += ex;
    }
    wV[(size_t)dd * 128 + o] = num / (den + 1e-16f);
}

// ---------------------------------------------------------------------------
extern "C" void kernel_launch(void* const* d_in, const int* in_sizes, int n_in,
                              void* d_out, int out_size, void* d_ws, size_t ws_size,
                              hipStream_t stream)
{
    const float* x         = (const float*)d_in[0];
    const int*   edge_idx  = (const int*)d_in[1];
    const float* rrwp      = (const float*)d_in[2];
    const float* edge_attr = (const float*)d_in[3];
    const float* Qw        = (const float*)d_in[4];
    const float* Qb        = (const float*)d_in[5];
    const float* Kw        = (const float*)d_in[6];
    const float* Kb        = (const float*)d_in[7];
    const float* Vw        = (const float*)d_in[8];
    const float* Vb        = (const float*)d_in[9];
    const float* Ew        = (const float*)d_in[10];
    const float* Eb        = (const float*)d_in[11];
    const float* wew       = (const float*)d_in[12];
    const float* web       = (const float*)d_in[13];
    const float* Wang      = (const float*)d_in[14];

    const int* srcI = edge_idx;
    const int* dstI = edge_idx + NE;

    float* wV = (float*)d_out;                       // N * 128
    float* wE = wV + (size_t)N * 128;                // NE * 128

    float* ws   = (float*)d_ws;
    float* Qh   = ws;                                // N*128
    float* Kh   = Qh + (size_t)N * 128;
    float* Vh   = Kh + (size_t)N * 128;
    float* exO  = Vh + (size_t)N * 128;              // NE*8
    int* cnt      = (int*)(exO + (size_t)NE * 8);    // N
    int* rowstart = cnt + N;                         // N+1
    int* cursor   = rowstart + (N + 1);              // N
    int* elist    = cursor + N;                      // NE

    hipMemsetAsync(cnt, 0, (size_t)N * sizeof(int), stream);
    hipMemsetAsync(cursor, 0, (size_t)N * sizeof(int), stream);

    qkv_rope_kernel<<<(N + NPB - 1) / NPB, 256, 0, stream>>>(
        x, rrwp, Qw, Qb, Kw, Kb, Vw, Vb, Wang, Qh, Kh, Vh);

    count_kernel<<<(NE + 255) / 256, 256, 0, stream>>>(dstI, cnt);
    scan_kernel<<<1, 1024, 0, stream>>>(cnt, rowstart);
    scatter_kernel<<<(NE + 255) / 256, 256, 0, stream>>>(dstI, rowstart, cursor, elist);

    edge_gemm_kernel<<<(NE + BE - 1) / BE, 256, 0, stream>>>(
        edge_attr, srcI, dstI, Qh, Kh, Ew, Eb, wew, web, wE, exO);

    wv_kernel<<<(N + 1) / 2, 256, 0, stream>>>(
        srcI, elist, rowstart, Vh, exO, wV);
}

// Round 3
// 1638.071 us; speedup vs baseline: 4.8284x; 1.1908x over previous
//
#include <hip/hip_runtime.h>
#include <hip/hip_bf16.h>
#include <math.h>

constexpr int N    = 50000;
constexpr int NE   = 500000;
constexpr int IN   = 128;
constexpr int H    = 8;
constexpr int D    = 16;
constexpr int DSEM = 4;
constexpr int KS   = 21;
constexpr float CLAMP = 5.0f;

// ---------------------------------------------------------------------------
// Ew transpose: EwT[k][o] = Ew[o][k]   (256x128 -> 128x256)
// ---------------------------------------------------------------------------
__global__ __launch_bounds__(256) void transpose_ew_kernel(
    const float* __restrict__ Ew, float* __restrict__ EwT)
{
    int k = blockIdx.x;        // 0..127
    int o = threadIdx.x;       // 0..255
    EwT[k * 256 + o] = Ew[(size_t)o * 128 + k];
}

// ---------------------------------------------------------------------------
// K1: fused QKV projection + RoPE.  16 nodes per 256-thread block.
// Thread t: fixed node nl = t&15, output-slot ob = t>>4; 24 outputs/thread,
// sx row chunked through registers (32 b128 LDS reads total).
// ---------------------------------------------------------------------------
constexpr int NPB = 16;

__global__ __launch_bounds__(256) void qkv_rope_kernel(
    const float* __restrict__ x, const float* __restrict__ rrwp,
    const float* __restrict__ Qw, const float* __restrict__ Qb,
    const float* __restrict__ Kw, const float* __restrict__ Kb,
    const float* __restrict__ Vw, const float* __restrict__ Vb,
    const float* __restrict__ Wang,
    float* __restrict__ Qh, float* __restrict__ Kh, float* __restrict__ Vh)
{
    __shared__ float sx[NPB][132];
    __shared__ float sout[NPB][388];
    __shared__ float srr[NPB][24];
    __shared__ float sc[NPB][48];
    __shared__ float ss[NPB][48];

    const int nb = blockIdx.x * NPB;
    const int t  = threadIdx.x;

    // stage x rows (float4, coalesced)
    #pragma unroll
    for (int rr = 0; rr < 2; rr++) {
        int i = rr * 256 + t;
        int nl = i >> 5, k4 = (i & 31) * 4;
        int n = nb + nl;
        float4 v = (n < N) ? *(const float4*)(x + (size_t)n * 128 + k4)
                           : make_float4(0.f, 0.f, 0.f, 0.f);
        *(float4*)(&sx[nl][k4]) = v;
    }
    for (int i = t; i < NPB * KS; i += 256) {
        int nl = i / KS, k = i % KS;
        int n = nb + nl;
        srr[nl][k] = (n < N) ? rrwp[(size_t)n * KS + k] : 0.0f;
    }
    __syncthreads();

    const int nl = t & 15;
    const int ob = t >> 4;
    float acc[24];
    #pragma unroll
    for (int r = 0; r < 24; r++) acc[r] = 0.0f;

    #pragma unroll 1
    for (int kc = 0; kc < 128; kc += 32) {
        float4 xr[8];
        #pragma unroll
        for (int q = 0; q < 8; q++) xr[q] = *(const float4*)(&sx[nl][kc + 4 * q]);
        #pragma unroll
        for (int rep = 0; rep < 24; rep++) {
            int mat = rep >> 3;
            int row = (rep & 7) * 16 + ob;
            const float* wb = (mat == 0 ? Qw : mat == 1 ? Kw : Vw) + (size_t)row * 128 + kc;
            const float4* w4 = (const float4*)wb;
            float s0 = 0.0f, s1 = 0.0f;
            #pragma unroll
            for (int q = 0; q < 4; q++) {
                float4 w0 = w4[q], w1 = w4[q + 4];
                float4 x0 = xr[q], x1 = xr[q + 4];
                s0 = fmaf(x0.x, w0.x, s0); s0 = fmaf(x0.y, w0.y, s0);
                s0 = fmaf(x0.z, w0.z, s0); s0 = fmaf(x0.w, w0.w, s0);
                s1 = fmaf(x1.x, w1.x, s1); s1 = fmaf(x1.y, w1.y, s1);
                s1 = fmaf(x1.z, w1.z, s1); s1 = fmaf(x1.w, w1.w, s1);
            }
            acc[rep] += s0 + s1;
        }
    }
    #pragma unroll
    for (int rep = 0; rep < 24; rep++) {
        int mat = rep >> 3;
        int row = (rep & 7) * 16 + ob;
        float b = (mat == 0 ? Qb : mat == 1 ? Kb : Vb)[row];
        sout[nl][mat * 128 + row] = acc[rep] + b;
    }
    __syncthreads();

    for (int i = t; i < NPB * 48; i += 256) {
        int nll = i / 48, a = i % 48;
        int h = a / 6, r = a % 6;
        float av = 0.0f;
        #pragma unroll
        for (int k = 0; k < KS; k++)
            av = fmaf(srr[nll][k], Wang[(size_t)(h * KS + k) * 6 + r], av);
        float sv, cv;
        sincosf(av, &sv, &cv);
        sc[nll][a] = cv;
        ss[nll][a] = sv;
    }
    __syncthreads();

    for (int i = t; i < NPB * 384; i += 256) {
        int nll = i / 384, o = i % 384;
        int n = nb + nll;
        if (n >= N) continue;
        int mat = o >> 7;
        int oo  = o & 127;
        int h = oo >> 4, d = oo & 15;
        float val;
        if (mat == 2 || d < DSEM) {
            val = sout[nll][o];
        } else {
            int i2 = (d - DSEM) >> 1;
            float c  = sc[nll][h * 6 + i2];
            float s2 = ss[nll][h * 6 + i2];
            int base = (mat << 7) + h * 16 + DSEM + 2 * i2;
            float xe = sout[nll][base];
            float xo = sout[nll][base + 1];
            val = ((d & 1) == 0) ? (xe * c - xo * s2) : (xe * s2 + xo * c);
        }
        float* dp = (mat == 0) ? Qh : (mat == 1) ? Kh : Vh;
        dp[(size_t)n * 128 + oo] = val;
    }
}

// ---------------------------------------------------------------------------
// K2: LDS-tiled fp32 GEMM, conflict-free mapping.
// Thread (tx,ty): edges 4*ty+r, outputs o = u*64 + tx*4 + j.
// ---------------------------------------------------------------------------
constexpr int BE    = 64;
constexpr int SA_S  = 36;     // sA   [64][36]
constexpr int SW_S  = 260;    // sW   [32][260]
constexpr int SWE_S = 132;    // sWe  [8][132]
constexpr int SO_S  = 292;    // sOut [64][292], per-head stride 36
constexpr int SH_S  = 36;

__global__ __launch_bounds__(256, 2) void edge_gemm_kernel(
    const float* __restrict__ edge_attr,
    const int* __restrict__ srcI, const int* __restrict__ dstI,
    const float* __restrict__ Qh, const float* __restrict__ Kh,
    const float* __restrict__ EwT, const float* __restrict__ Eb,
    const float* __restrict__ wew, const float* __restrict__ web,
    float* __restrict__ wE, float* __restrict__ exOut)
{
    __shared__ float smem[64 * SO_S + 512];     // 78.8 KB -> 2 blocks/CU
    float* sA    = smem;                         // [64][36]   (GEMM phase)
    float* sW    = smem + 2304;                  // [32][260]
    float* sWe   = smem + 2304 + 8320;           // [8][132]
    float* sOut  = smem;                         // [64][292]  (epilogue phase)
    float* sBias = smem + 64 * SO_S;             // [64][8]

    const int t   = threadIdx.x;
    const int tx  = t & 15;
    const int ty  = t >> 4;
    const int eb0 = blockIdx.x * BE;

    for (int i = t; i < 8 * 128; i += 256) {
        int h = i >> 7, k = i & 127;
        sWe[h * SWE_S + k] = wew[h * 128 + k];
    }

    float acc[4][4][4];
    #pragma unroll
    for (int r = 0; r < 4; r++)
        #pragma unroll
        for (int u = 0; u < 4; u++)
            #pragma unroll
            for (int j = 0; j < 4; j++) acc[r][u][j] = 0.0f;
    float eb_acc[2] = {0.0f, 0.0f};

    #pragma unroll 1
    for (int kc = 0; kc < 128; kc += 32) {
        __syncthreads();
        // stage A: 64 edges x 32 k (float4, coalesced, 2-way LDS)
        #pragma unroll
        for (int rr = 0; rr < 2; rr++) {
            int i = rr * 256 + t;
            int e = i >> 3, k4 = (i & 7) * 4;
            int ge = eb0 + e;
            float4 v = (ge < NE) ? *(const float4*)(edge_attr + (size_t)ge * 128 + kc + k4)
                                 : make_float4(0.f, 0.f, 0.f, 0.f);
            *(float4*)(sA + e * SA_S + k4) = v;
        }
        // stage W from EwT (k-major): per wave k const, o contiguous
        #pragma unroll
        for (int rr = 0; rr < 8; rr++) {
            int i = rr * 256 + t;
            int k = i >> 6, o4 = (i & 63) * 4;
            float4 v = *(const float4*)(EwT + (size_t)(kc + k) * 256 + o4);
            *(float4*)(sW + k * SW_S + o4) = v;
        }
        __syncthreads();

        // e_bias partials: 2 (e,h) pairs per thread, vectorized
        #pragma unroll
        for (int r = 0; r < 2; r++) {
            int id = t * 2 + r;
            int e = id >> 3, h = id & 7;
            const float* ap = sA + e * SA_S;
            const float* wp = sWe + h * SWE_S + kc;
            float s0 = 0.0f, s1 = 0.0f;
            #pragma unroll
            for (int q = 0; q < 4; q++) {
                float4 a0 = *(const float4*)(ap + 8 * q);
                float4 w0 = *(const float4*)(wp + 8 * q);
                float4 a1 = *(const float4*)(ap + 8 * q + 4);
                float4 w1 = *(const float4*)(wp + 8 * q + 4);
                s0 = fmaf(a0.x, w0.x, s0); s0 = fmaf(a0.y, w0.y, s0);
                s0 = fmaf(a0.z, w0.z, s0); s0 = fmaf(a0.w, w0.w, s0);
                s1 = fmaf(a1.x, w1.x, s1); s1 = fmaf(a1.y, w1.y, s1);
                s1 = fmaf(a1.z, w1.z, s1); s1 = fmaf(a1.w, w1.w, s1);
            }
            eb_acc[r] += s0 + s1;
        }

        // GEMM: 4-k groups; a-fragments via b128
        #pragma unroll 2
        for (int k4 = 0; k4 < 32; k4 += 4) {
            float4 av4[4];
            #pragma unroll
            for (int r = 0; r < 4; r++)
                av4[r] = *(const float4*)(sA + (4 * ty + r) * SA_S + k4);
            const float* avf = (const float*)av4;
            #pragma unroll
            for (int kk = 0; kk < 4; kk++) {
                float4 w[4];
                #pragma unroll
                for (int u = 0; u < 4; u++)
                    w[u] = *(const float4*)(sW + (k4 + kk) * SW_S + u * 64 + tx * 4);
                #pragma unroll
                for (int r = 0; r < 4; r++) {
                    float ar = avf[r * 4 + kk];
                    #pragma unroll
                    for (int u = 0; u < 4; u++) {
                        acc[r][u][0] = fmaf(ar, w[u].x, acc[r][u][0]);
                        acc[r][u][1] = fmaf(ar, w[u].y, acc[r][u][1]);
                        acc[r][u][2] = fmaf(ar, w[u].z, acc[r][u][2]);
                        acc[r][u][3] = fmaf(ar, w[u].w, acc[r][u][3]);
                    }
                }
            }
        }
    }

    // finalize e_bias
    #pragma unroll
    for (int r = 0; r < 2; r++) {
        int id = t * 2 + r;
        int e = id >> 3, h = id & 7;
        sBias[e * 8 + h] = eb_acc[r] + web[h];
    }
    __syncthreads();            // all GEMM-phase LDS reads complete

    // write E_proj + Eb into sOut (head stride 36)
    #pragma unroll
    for (int u = 0; u < 4; u++) {
        int o4 = u * 64 + tx * 4;
        int h = o4 >> 5, col = o4 & 31;
        float4 ebv = *(const float4*)(Eb + o4);
        #pragma unroll
        for (int r = 0; r < 4; r++) {
            int e = 4 * ty + r;
            *(float4*)(sOut + e * SO_S + h * SH_S + col) =
                make_float4(acc[r][u][0] + ebv.x, acc[r][u][1] + ebv.y,
                            acc[r][u][2] + ebv.z, acc[r][u][3] + ebv.w);
        }
    }
    __syncthreads();

    // per-edge epilogue: 4 threads/edge, 2 heads each
    const int e_l = t >> 2;
    const int hp  = t & 3;
    const int ge  = eb0 + e_l;
    if (ge < NE) {
        const int s  = srcI[ge];
        const int dd = dstI[ge];
        const float4* K4 = (const float4*)(Kh + (size_t)s  * 128);
        const float4* Q4 = (const float4*)(Qh + (size_t)dd * 128);
        const float inv_s4  = 0.5f;
        const float inv_s12 = 0.28867513459481288f;
        #pragma unroll
        for (int hi = 0; hi < 2; hi++) {
            int hh = 2 * hp + hi;
            float4 kf[4], qf[4];
            #pragma unroll
            for (int j = 0; j < 4; j++) { kf[j] = K4[hh * 4 + j]; qf[j] = Q4[hh * 4 + j]; }
            float sem = kf[0].x*qf[0].x + kf[0].y*qf[0].y + kf[0].z*qf[0].z + kf[0].w*qf[0].w;
            float stl = 0.0f;
            #pragma unroll
            for (int j = 1; j < 4; j++)
                stl += kf[j].x*qf[j].x + kf[j].y*qf[j].y + kf[j].z*qf[j].z + kf[j].w*qf[j].w;
            float logit = sem * inv_s4 + stl * inv_s12 + sBias[e_l * 8 + hh];
            logit = fminf(fmaxf(logit, -CLAMP), CLAMP);
            float ex = __expf(logit);
            exOut[(size_t)ge * 8 + hh] = ex;
            const float* srow = sOut + e_l * SO_S + hh * SH_S;
            #pragma unroll
            for (int u = 0; u < 4; u++) {
                float4 A = *(const float4*)(srow + 4 * u);
                float4 B = *(const float4*)(srow + 16 + 4 * u);
                float4 kq = make_float4(kf[u].x + qf[u].x, kf[u].y + qf[u].y,
                                        kf[u].z + qf[u].z, kf[u].w + qf[u].w);
                float4 o;
                float v;
                v = kq.x * A.x; o.x = copysignf(sqrtf(fabsf(v)), v) + B.x;
                v = kq.y * A.y; o.y = copysignf(sqrtf(fabsf(v)), v) + B.y;
                v = kq.z * A.z; o.z = copysignf(sqrtf(fabsf(v)), v) + B.z;
                v = kq.w * A.w; o.w = copysignf(sqrtf(fabsf(v)), v) + B.w;
                *(float4*)(wE + (size_t)ge * 128 + hh * 16 + 4 * u) = o;
            }
        }
    }
}

// ---------------------------------------------------------------------------
// CSR build: count -> multi-block scan -> scatter
// ---------------------------------------------------------------------------
__global__ __launch_bounds__(256) void count_kernel(
    const int* __restrict__ dstI, int* __restrict__ cnt)
{
    int e = blockIdx.x * 256 + threadIdx.x;
    if (e < NE) atomicAdd(&cnt[dstI[e]], 1);
}

__global__ __launch_bounds__(1024) void block_scan_kernel(
    const int* __restrict__ cnt, int* __restrict__ rowstart, int* __restrict__ bsum)
{
    __shared__ int sbuf[1024];
    const int b = blockIdx.x, t = threadIdx.x;
    const int i = b * 1024 + t;
    sbuf[t] = (i < N) ? cnt[i] : 0;
    __syncthreads();
    for (int off = 1; off < 1024; off <<= 1) {
        int xv = sbuf[t];
        int yv = (t >= off) ? sbuf[t - off] : 0;
        __syncthreads();
        sbuf[t] = xv + yv;
        __syncthreads();
    }
    if (i < N) rowstart[i + 1] = sbuf[t];
    if (t == 1023) bsum[b] = sbuf[1023];
}

__global__ void scan_totals_kernel(int* __restrict__ bsum, int nb)
{
    if (threadIdx.x == 0 && blockIdx.x == 0) {
        int run = 0;
        for (int b = 0; b < nb; b++) { int v = bsum[b]; bsum[b] = run; run += v; }
    }
}

__global__ __launch_bounds__(1024) void add_offsets_kernel(
    const int* __restrict__ bsum, int* __restrict__ rowstart)
{
    const int b = blockIdx.x, t = threadIdx.x;
    const int i = b * 1024 + t;
    if (i < N) rowstart[i + 1] += bsum[b];
    if (b == 0 && t == 0) rowstart[0] = 0;
}

__global__ __launch_bounds__(256) void scatter_kernel(
    const int* __restrict__ dstI, const int* __restrict__ rowstart,
    int* __restrict__ cursor, int* __restrict__ elist)
{
    int e = blockIdx.x * 256 + threadIdx.x;
    if (e >= NE) return;
    int d = dstI[e];
    int pos = atomicAdd(&cursor[d], 1);
    elist[rowstart[d] + pos] = e;
}

// ---------------------------------------------------------------------------
// K3: gather-based wV
// ---------------------------------------------------------------------------
__global__ __launch_bounds__(256) void wv_kernel(
    const int* __restrict__ srcI, const int* __restrict__ elist,
    const int* __restrict__ rowstart, const float* __restrict__ Vh,
    const float* __restrict__ exOut, float* __restrict__ wV)
{
    const int dd = blockIdx.x * 2 + (threadIdx.x >> 7);
    const int o  = threadIdx.x & 127;
    if (dd >= N) return;
    const int h  = o >> 4;
    const int st = rowstart[dd];
    const int en = rowstart[dd + 1];
    float den = 0.0f, num = 0.0f;
    for (int i = st; i < en; i++) {
        int e = elist[i];
        float ex = exOut[(size_t)e * 8 + h];
        int s = srcI[e];
        num = fmaf(Vh[(size_t)s * 128 + o], ex, num);
        den += ex;
    }
    wV[(size_t)dd * 128 + o] = num / (den + 1e-16f);
}

// ---------------------------------------------------------------------------
extern "C" void kernel_launch(void* const* d_in, const int* in_sizes, int n_in,
                              void* d_out, int out_size, void* d_ws, size_t ws_size,
                              hipStream_t stream)
{
    const float* x         = (const float*)d_in[0];
    const int*   edge_idx  = (const int*)d_in[1];
    const float* rrwp      = (const float*)d_in[2];
    const float* edge_attr = (const float*)d_in[3];
    const float* Qw        = (const float*)d_in[4];
    const float* Qb        = (const float*)d_in[5];
    const float* Kw        = (const float*)d_in[6];
    const float* Kb        = (const float*)d_in[7];
    const float* Vw        = (const float*)d_in[8];
    const float* Vb        = (const float*)d_in[9];
    const float* Ew        = (const float*)d_in[10];
    const float* Eb        = (const float*)d_in[11];
    const float* wew       = (const float*)d_in[12];
    const float* web       = (const float*)d_in[13];
    const float* Wang      = (const float*)d_in[14];

    const int* srcI = edge_idx;
    const int* dstI = edge_idx + NE;

    float* wV = (float*)d_out;                       // N * 128
    float* wE = wV + (size_t)N * 128;                // NE * 128

    float* ws   = (float*)d_ws;
    float* Qh   = ws;                                // N*128
    float* Kh   = Qh + (size_t)N * 128;
    float* Vh   = Kh + (size_t)N * 128;
    float* exO  = Vh + (size_t)N * 128;              // NE*8
    int* cnt      = (int*)(exO + (size_t)NE * 8);    // N
    int* rowstart = cnt + N;                         // N+1
    int* cursor   = rowstart + (N + 1);              // N
    int* elist    = cursor + N;                      // NE
    int* bsum     = elist + NE;                      // 64
    float* EwT    = (float*)(bsum + 64);             // 128*256

    const int NB_SCAN = (N + 1023) / 1024;           // 49

    hipMemsetAsync(cnt, 0, (size_t)N * sizeof(int), stream);
    hipMemsetAsync(cursor, 0, (size_t)N * sizeof(int), stream);

    transpose_ew_kernel<<<128, 256, 0, stream>>>(Ew, EwT);

    qkv_rope_kernel<<<(N + NPB - 1) / NPB, 256, 0, stream>>>(
        x, rrwp, Qw, Qb, Kw, Kb, Vw, Vb, Wang, Qh, Kh, Vh);

    count_kernel<<<(NE + 255) / 256, 256, 0, stream>>>(dstI, cnt);
    block_scan_kernel<<<NB_SCAN, 1024, 0, stream>>>(cnt, rowstart, bsum);
    scan_totals_kernel<<<1, 64, 0, stream>>>(bsum, NB_SCAN);
    add_offsets_kernel<<<NB_SCAN, 1024, 0, stream>>>(bsum, rowstart);
    scatter_kernel<<<(NE + 255) / 256, 256, 0, stream>>>(dstI, rowstart, cursor, elist);

    edge_gemm_kernel<<<(NE + BE - 1) / BE, 256, 0, stream>>>(
        edge_attr, srcI, dstI, Qh, Kh, EwT, Eb, wew, web, wE, exO);

    wv_kernel<<<(N + 1) / 2, 256, 0, stream>>>(
        srcI, elist, rowstart, Vh, exO, wV);
}

// Round 4
// 1344.374 us; speedup vs baseline: 5.8832x; 1.2185x over previous
//
#include <hip/hip_runtime.h>
#include <hip/hip_bf16.h>
#include <math.h>

constexpr int N    = 50000;
constexpr int NE   = 500000;
constexpr int IN   = 128;
constexpr int H    = 8;
constexpr int D    = 16;
constexpr int DSEM = 4;
constexpr int KS   = 21;
constexpr float CLAMP = 5.0f;

typedef __attribute__((ext_vector_type(8))) __bf16 bf16x8;
typedef __attribute__((ext_vector_type(4))) float  f32x4;

__device__ inline f32x4 mfma16(bf16x8 a, bf16x8 b, f32x4 c) {
    return __builtin_amdgcn_mfma_f32_16x16x32_bf16(a, b, c, 0, 0, 0);
}

__device__ inline void split_bf16(float f, unsigned& hi, unsigned& lo) {
    unsigned u = __float_as_uint(f);
    hi = (u + 0x7FFFu + ((u >> 16) & 1u)) >> 16;
    float fl = f - __uint_as_float(hi << 16);
    unsigned ul = __float_as_uint(fl);
    lo = (ul + 0x7FFFu + ((ul >> 16) & 1u)) >> 16;
}

// pack two consecutive elements (a=elem j, b=elem j+1) into hi/lo u32 words
__device__ inline void split2(float a, float b, unsigned& hi, unsigned& lo) {
    unsigned ha, la, hb, lb;
    split_bf16(a, ha, la);
    split_bf16(b, hb, lb);
    hi = ha | (hb << 16);
    lo = la | (lb << 16);
}

// ---------------------------------------------------------------------------
// prep_w: split Ew (256x128 fp32) into bf16 hi/lo, stored FRAGMENT-LINEAR:
// element index ((ot*4 + ks)*64 + l)*8 + j  <-  Ew[16*ot + (l&15)][32*ks + 8*(l>>4) + j]
// ---------------------------------------------------------------------------
__global__ __launch_bounds__(256) void prep_w_kernel(
    const float* __restrict__ Ew, ushort* __restrict__ EwHiF, ushort* __restrict__ EwLoF)
{
    int tid = blockIdx.x * 256 + threadIdx.x;          // 0..4095
    int l  = tid & 63;
    int ks = (tid >> 6) & 3;
    int ot = tid >> 8;
    int row = 16 * ot + (l & 15);
    int col = 32 * ks + 8 * (l >> 4);
    const float* src = Ew + (size_t)row * 128 + col;
    float4 f0 = *(const float4*)(src);
    float4 f1 = *(const float4*)(src + 4);
    unsigned H0,L0,H1,L1,H2,L2,H3,L3;
    split2(f0.x, f0.y, H0, L0);
    split2(f0.z, f0.w, H1, L1);
    split2(f1.x, f1.y, H2, L2);
    split2(f1.z, f1.w, H3, L3);
    *(uint4*)(EwHiF + (size_t)tid * 8) = make_uint4(H0, H1, H2, H3);
    *(uint4*)(EwLoF + (size_t)tid * 8) = make_uint4(L0, L1, L2, L3);
}

// ---------------------------------------------------------------------------
// K1: fused QKV projection + RoPE (unchanged, known-good)
// ---------------------------------------------------------------------------
constexpr int NPB = 16;

__global__ __launch_bounds__(256) void qkv_rope_kernel(
    const float* __restrict__ x, const float* __restrict__ rrwp,
    const float* __restrict__ Qw, const float* __restrict__ Qb,
    const float* __restrict__ Kw, const float* __restrict__ Kb,
    const float* __restrict__ Vw, const float* __restrict__ Vb,
    const float* __restrict__ Wang,
    float* __restrict__ Qh, float* __restrict__ Kh, float* __restrict__ Vh)
{
    __shared__ float sx[NPB][132];
    __shared__ float sout[NPB][388];
    __shared__ float srr[NPB][24];
    __shared__ float sc[NPB][48];
    __shared__ float ss[NPB][48];

    const int nb = blockIdx.x * NPB;
    const int t  = threadIdx.x;

    #pragma unroll
    for (int rr = 0; rr < 2; rr++) {
        int i = rr * 256 + t;
        int nl = i >> 5, k4 = (i & 31) * 4;
        int n = nb + nl;
        float4 v = (n < N) ? *(const float4*)(x + (size_t)n * 128 + k4)
                           : make_float4(0.f, 0.f, 0.f, 0.f);
        *(float4*)(&sx[nl][k4]) = v;
    }
    for (int i = t; i < NPB * KS; i += 256) {
        int nl = i / KS, k = i % KS;
        int n = nb + nl;
        srr[nl][k] = (n < N) ? rrwp[(size_t)n * KS + k] : 0.0f;
    }
    __syncthreads();

    const int nl = t & 15;
    const int ob = t >> 4;
    float acc[24];
    #pragma unroll
    for (int r = 0; r < 24; r++) acc[r] = 0.0f;

    #pragma unroll 1
    for (int kc = 0; kc < 128; kc += 32) {
        float4 xr[8];
        #pragma unroll
        for (int q = 0; q < 8; q++) xr[q] = *(const float4*)(&sx[nl][kc + 4 * q]);
        #pragma unroll
        for (int rep = 0; rep < 24; rep++) {
            int mat = rep >> 3;
            int row = (rep & 7) * 16 + ob;
            const float* wb = (mat == 0 ? Qw : mat == 1 ? Kw : Vw) + (size_t)row * 128 + kc;
            const float4* w4 = (const float4*)wb;
            float s0 = 0.0f, s1 = 0.0f;
            #pragma unroll
            for (int q = 0; q < 4; q++) {
                float4 w0 = w4[q], w1 = w4[q + 4];
                float4 x0 = xr[q], x1 = xr[q + 4];
                s0 = fmaf(x0.x, w0.x, s0); s0 = fmaf(x0.y, w0.y, s0);
                s0 = fmaf(x0.z, w0.z, s0); s0 = fmaf(x0.w, w0.w, s0);
                s1 = fmaf(x1.x, w1.x, s1); s1 = fmaf(x1.y, w1.y, s1);
                s1 = fmaf(x1.z, w1.z, s1); s1 = fmaf(x1.w, w1.w, s1);
            }
            acc[rep] += s0 + s1;
        }
    }
    #pragma unroll
    for (int rep = 0; rep < 24; rep++) {
        int mat = rep >> 3;
        int row = (rep & 7) * 16 + ob;
        float b = (mat == 0 ? Qb : mat == 1 ? Kb : Vb)[row];
        sout[nl][mat * 128 + row] = acc[rep] + b;
    }
    __syncthreads();

    for (int i = t; i < NPB * 48; i += 256) {
        int nll = i / 48, a = i % 48;
        int h = a / 6, r = a % 6;
        float av = 0.0f;
        #pragma unroll
        for (int k = 0; k < KS; k++)
            av = fmaf(srr[nll][k], Wang[(size_t)(h * KS + k) * 6 + r], av);
        float sv, cv;
        sincosf(av, &sv, &cv);
        sc[nll][a] = cv;
        ss[nll][a] = sv;
    }
    __syncthreads();

    for (int i = t; i < NPB * 384; i += 256) {
        int nll = i / 384, o = i % 384;
        int n = nb + nll;
        if (n >= N) continue;
        int mat = o >> 7;
        int oo  = o & 127;
        int h = oo >> 4, d = oo & 15;
        float val;
        if (mat == 2 || d < DSEM) {
            val = sout[nll][o];
        } else {
            int i2 = (d - DSEM) >> 1;
            float c  = sc[nll][h * 6 + i2];
            float s2 = ss[nll][h * 6 + i2];
            int base = (mat << 7) + h * 16 + DSEM + 2 * i2;
            float xe = sout[nll][base];
            float xo = sout[nll][base + 1];
            val = ((d & 1) == 0) ? (xe * c - xo * s2) : (xe * s2 + xo * c);
        }
        float* dp = (mat == 0) ? Qh : (mat == 1) ? Kh : Vh;
        dp[(size_t)n * 128 + oo] = val;
    }
}

// ---------------------------------------------------------------------------
// K2: split-bf16 MFMA edge GEMM.  Block = 64 edges x 256 outs, K in 2 chunks
// of 64.  LDS: W hi/lo frag (64 KB, linear copy from prep_w) + A hi/lo frag
// (16 KB, converted in-kernel) = 80 KB -> 2 blocks/CU.
// Wave w: o-tiles 4w..4w+3 x all 64 edges; acc[g][otl] f32x4.
// E_proj = Ahi*Whi + Alo*Whi + Ahi*Wlo  (3-term split, err ~1e-4).
// ---------------------------------------------------------------------------
constexpr int WHI_OFF = 0;        // [16 ot][2 ks2][64 l][16 B]
constexpr int WLO_OFF = 32768;
constexpr int AHI_OFF = 65536;    // [4 g][2 ks2][64 l][16 B]
constexpr int ALO_OFF = 73728;
constexpr int SO_STRIDE = 268;    // fp32 words; 4*268 % 32 == 16 -> 2-way max

__global__ __launch_bounds__(256, 2) void edge_gemm_kernel(
    const float* __restrict__ edge_attr,
    const int* __restrict__ srcI, const int* __restrict__ dstI,
    const float* __restrict__ Qh, const float* __restrict__ Kh,
    const ushort* __restrict__ EwHiF, const ushort* __restrict__ EwLoF,
    const float* __restrict__ Eb,
    const float* __restrict__ wew, const float* __restrict__ web,
    float* __restrict__ wE, float* __restrict__ exOut)
{
    __shared__ __align__(16) char smem[81920];

    const int t    = threadIdx.x;
    const int wid  = t >> 6;
    const int lane = t & 63;
    const int eb0  = blockIdx.x * 64;

    f32x4 acc[4][4];
    #pragma unroll
    for (int g = 0; g < 4; g++)
        #pragma unroll
        for (int o = 0; o < 4; o++)
            acc[g][o] = (f32x4){0.f, 0.f, 0.f, 0.f};

    // A-staging mapping: thread -> (edge, k-quarter)
    const int se   = t >> 2;        // edge 0..63
    const int sq   = t & 3;         // 16-k quarter within 64-k chunk
    const int sr   = se & 15;
    const int sg   = se >> 4;
    const int sks2 = sq >> 1;
    const int slb  = 2 * (sq & 1);
    const int sge  = eb0 + se;
    const int abase = ((sg * 2 + sks2) * 64 + slb * 16 + sr) * 16;

    #pragma unroll 1
    for (int c = 0; c < 2; c++) {
        // ---- stage W chunk c (linear copy of frag-ordered bf16) ----
        #pragma unroll
        for (int r = 0; r < 8; r++) {
            int i = r * 256 + t;                 // 0..2047 float4s
            int ot = i >> 7;
            size_t src = (size_t)ot * 4096 + (size_t)c * 2048 + (size_t)(i & 127) * 16;
            *(float4*)(smem + WHI_OFF + i * 16) = *(const float4*)((const char*)EwHiF + src);
            *(float4*)(smem + WLO_OFF + i * 16) = *(const float4*)((const char*)EwLoF + src);
        }
        // ---- stage A chunk c (fp32 -> bf16 hi/lo fragments) ----
        {
            float4 v0, v1, v2, v3;
            if (sge < NE) {
                const float4* ar = (const float4*)(edge_attr + (size_t)sge * 128 + c * 64 + sq * 16);
                v0 = ar[0]; v1 = ar[1]; v2 = ar[2]; v3 = ar[3];
            } else {
                v0 = v1 = v2 = v3 = make_float4(0.f, 0.f, 0.f, 0.f);
            }
            unsigned H0,L0,H1,L1,H2,L2,H3,L3,H4,L4,H5,L5,H6,L6,H7,L7;
            split2(v0.x, v0.y, H0, L0); split2(v0.z, v0.w, H1, L1);
            split2(v1.x, v1.y, H2, L2); split2(v1.z, v1.w, H3, L3);
            split2(v2.x, v2.y, H4, L4); split2(v2.z, v2.w, H5, L5);
            split2(v3.x, v3.y, H6, L6); split2(v3.z, v3.w, H7, L7);
            *(uint4*)(smem + AHI_OFF + abase)       = make_uint4(H0, H1, H2, H3);
            *(uint4*)(smem + AHI_OFF + abase + 256) = make_uint4(H4, H5, H6, H7);
            *(uint4*)(smem + ALO_OFF + abase)       = make_uint4(L0, L1, L2, L3);
            *(uint4*)(smem + ALO_OFF + abase + 256) = make_uint4(L4, L5, L6, L7);
        }
        __syncthreads();

        // ---- MFMA GEMM over this chunk ----
        #pragma unroll
        for (int ks2 = 0; ks2 < 2; ks2++) {
            bf16x8 Ah[4], Al[4];
            #pragma unroll
            for (int g = 0; g < 4; g++) {
                int off = ((g * 2 + ks2) * 64 + lane) * 16;
                Ah[g] = *(const bf16x8*)(smem + AHI_OFF + off);
                Al[g] = *(const bf16x8*)(smem + ALO_OFF + off);
            }
            #pragma unroll
            for (int otl = 0; otl < 4; otl++) {
                int woff = (((wid * 4 + otl) * 2 + ks2) * 64 + lane) * 16;
                bf16x8 Bh = *(const bf16x8*)(smem + WHI_OFF + woff);
                bf16x8 Bl = *(const bf16x8*)(smem + WLO_OFF + woff);
                #pragma unroll
                for (int g = 0; g < 4; g++) {
                    acc[g][otl] = mfma16(Ah[g], Bh, acc[g][otl]);
                    acc[g][otl] = mfma16(Al[g], Bh, acc[g][otl]);
                    acc[g][otl] = mfma16(Ah[g], Bl, acc[g][otl]);
                }
            }
        }
        __syncthreads();
    }

    // ---- acc -> sOut (+ Eb) ----
    // D layout: row = (lane>>4)*4 + jr (edge), col = lane&15 (o offset)
    float* sOut = (float*)smem;
    const int lr4 = (lane >> 4) * 4;
    const int lc  = lane & 15;
    #pragma unroll
    for (int otl = 0; otl < 4; otl++) {
        int o = (wid * 4 + otl) * 16 + lc;
        float ebv = Eb[o];
        #pragma unroll
        for (int g = 0; g < 4; g++) {
            int e = 16 * g + lr4;
            #pragma unroll
            for (int jr = 0; jr < 4; jr++)
                sOut[(e + jr) * SO_STRIDE + o] = acc[g][otl][jr] + ebv;
        }
    }
    __syncthreads();

    // ---- per-edge epilogue: fp32 e_bias + logit/exp + signed-sqrt wE ----
    const int e_l = t >> 2;
    const int hp  = t & 3;
    const int ge  = eb0 + e_l;
    if (ge < NE) {
        const int s  = srcI[ge];
        const int dd = dstI[ge];
        const int h0 = 2 * hp, h1 = 2 * hp + 1;

        // e_bias (fp32, exact): edge_attr row dot wew rows (L2-warm)
        const float4* ar = (const float4*)(edge_attr + (size_t)ge * 128);
        const float4* w0 = (const float4*)(wew + (size_t)h0 * 128);
        const float4* w1 = (const float4*)(wew + (size_t)h1 * 128);
        float b0 = 0.f, b1 = 0.f;
        #pragma unroll
        for (int k = 0; k < 32; k++) {
            float4 a = ar[k], u = w0[k], v = w1[k];
            b0 = fmaf(a.x, u.x, b0); b0 = fmaf(a.y, u.y, b0);
            b0 = fmaf(a.z, u.z, b0); b0 = fmaf(a.w, u.w, b0);
            b1 = fmaf(a.x, v.x, b1); b1 = fmaf(a.y, v.y, b1);
            b1 = fmaf(a.z, v.z, b1); b1 = fmaf(a.w, v.w, b1);
        }
        float ebias0 = b0 + web[h0];
        float ebias1 = b1 + web[h1];

        const float4* K4 = (const float4*)(Kh + (size_t)s  * 128);
        const float4* Q4 = (const float4*)(Qh + (size_t)dd * 128);
        const float inv_s4  = 0.5f;
        const float inv_s12 = 0.28867513459481288f;
        #pragma unroll
        for (int hi = 0; hi < 2; hi++) {
            int hh = 2 * hp + hi;
            float eb = (hi == 0) ? ebias0 : ebias1;
            float4 kf[4], qf[4];
            #pragma unroll
            for (int j = 0; j < 4; j++) { kf[j] = K4[hh * 4 + j]; qf[j] = Q4[hh * 4 + j]; }
            float sem = kf[0].x*qf[0].x + kf[0].y*qf[0].y + kf[0].z*qf[0].z + kf[0].w*qf[0].w;
            float stl = 0.0f;
            #pragma unroll
            for (int j = 1; j < 4; j++)
                stl += kf[j].x*qf[j].x + kf[j].y*qf[j].y + kf[j].z*qf[j].z + kf[j].w*qf[j].w;
            float logit = sem * inv_s4 + stl * inv_s12 + eb;
            logit = fminf(fmaxf(logit, -CLAMP), CLAMP);
            float ex = __expf(logit);
            exOut[(size_t)ge * 8 + hh] = ex;
            const float* srow = sOut + e_l * SO_STRIDE + hh * 32;
            #pragma unroll
            for (int u = 0; u < 4; u++) {
                float4 A = *(const float4*)(srow + 4 * u);
                float4 B = *(const float4*)(srow + 16 + 4 * u);
                float4 kq = make_float4(kf[u].x + qf[u].x, kf[u].y + qf[u].y,
                                        kf[u].z + qf[u].z, kf[u].w + qf[u].w);
                float4 o;
                float v;
                v = kq.x * A.x; o.x = copysignf(sqrtf(fabsf(v)), v) + B.x;
                v = kq.y * A.y; o.y = copysignf(sqrtf(fabsf(v)), v) + B.y;
                v = kq.z * A.z; o.z = copysignf(sqrtf(fabsf(v)), v) + B.z;
                v = kq.w * A.w; o.w = copysignf(sqrtf(fabsf(v)), v) + B.w;
                *(float4*)(wE + (size_t)ge * 128 + hh * 16 + 4 * u) = o;
            }
        }
    }
}

// ---------------------------------------------------------------------------
// CSR build: count -> multi-block scan -> scatter (unchanged)
// ---------------------------------------------------------------------------
__global__ __launch_bounds__(256) void count_kernel(
    const int* __restrict__ dstI, int* __restrict__ cnt)
{
    int e = blockIdx.x * 256 + threadIdx.x;
    if (e < NE) atomicAdd(&cnt[dstI[e]], 1);
}

__global__ __launch_bounds__(1024) void block_scan_kernel(
    const int* __restrict__ cnt, int* __restrict__ rowstart, int* __restrict__ bsum)
{
    __shared__ int sbuf[1024];
    const int b = blockIdx.x, t = threadIdx.x;
    const int i = b * 1024 + t;
    sbuf[t] = (i < N) ? cnt[i] : 0;
    __syncthreads();
    for (int off = 1; off < 1024; off <<= 1) {
        int xv = sbuf[t];
        int yv = (t >= off) ? sbuf[t - off] : 0;
        __syncthreads();
        sbuf[t] = xv + yv;
        __syncthreads();
    }
    if (i < N) rowstart[i + 1] = sbuf[t];
    if (t == 1023) bsum[b] = sbuf[1023];
}

__global__ void scan_totals_kernel(int* __restrict__ bsum, int nb)
{
    if (threadIdx.x == 0 && blockIdx.x == 0) {
        int run = 0;
        for (int b = 0; b < nb; b++) { int v = bsum[b]; bsum[b] = run; run += v; }
    }
}

__global__ __launch_bounds__(1024) void add_offsets_kernel(
    const int* __restrict__ bsum, int* __restrict__ rowstart)
{
    const int b = blockIdx.x, t = threadIdx.x;
    const int i = b * 1024 + t;
    if (i < N) rowstart[i + 1] += bsum[b];
    if (b == 0 && t == 0) rowstart[0] = 0;
}

__global__ __launch_bounds__(256) void scatter_kernel(
    const int* __restrict__ dstI, const int* __restrict__ rowstart,
    int* __restrict__ cursor, int* __restrict__ elist)
{
    int e = blockIdx.x * 256 + threadIdx.x;
    if (e >= NE) return;
    int d = dstI[e];
    int pos = atomicAdd(&cursor[d], 1);
    elist[rowstart[d] + pos] = e;
}

// ---------------------------------------------------------------------------
// K3: gather-based wV (unchanged)
// ---------------------------------------------------------------------------
__global__ __launch_bounds__(256) void wv_kernel(
    const int* __restrict__ srcI, const int* __restrict__ elist,
    const int* __restrict__ rowstart, const float* __restrict__ Vh,
    const float* __restrict__ exOut, float* __restrict__ wV)
{
    const int dd = blockIdx.x * 2 + (threadIdx.x >> 7);
    const int o  = threadIdx.x & 127;
    if (dd >= N) return;
    const int h  = o >> 4;
    const int st = rowstart[dd];
    const int en = rowstart[dd + 1];
    float den = 0.0f, num = 0.0f;
    for (int i = st; i < en; i++) {
        int e = elist[i];
        float ex = exOut[(size_t)e * 8 + h];
        int s = srcI[e];
        num = fmaf(Vh[(size_t)s * 128 + o], ex, num);
        den += ex;
    }
    wV[(size_t)dd * 128 + o] = num / (den + 1e-16f);
}

// ---------------------------------------------------------------------------
extern "C" void kernel_launch(void* const* d_in, const int* in_sizes, int n_in,
                              void* d_out, int out_size, void* d_ws, size_t ws_size,
                              hipStream_t stream)
{
    const float* x         = (const float*)d_in[0];
    const int*   edge_idx  = (const int*)d_in[1];
    const float* rrwp      = (const float*)d_in[2];
    const float* edge_attr = (const float*)d_in[3];
    const float* Qw        = (const float*)d_in[4];
    const float* Qb        = (const float*)d_in[5];
    const float* Kw        = (const float*)d_in[6];
    const float* Kb        = (const float*)d_in[7];
    const float* Vw        = (const float*)d_in[8];
    const float* Vb        = (const float*)d_in[9];
    const float* Ew        = (const float*)d_in[10];
    const float* Eb        = (const float*)d_in[11];
    const float* wew       = (const float*)d_in[12];
    const float* web       = (const float*)d_in[13];
    const float* Wang      = (const float*)d_in[14];

    const int* srcI = edge_idx;
    const int* dstI = edge_idx + NE;

    float* wV = (float*)d_out;                       // N * 128
    float* wE = wV + (size_t)N * 128;                // NE * 128

    // workspace layout (16-B aligned head for bf16 frag arrays)
    ushort* EwHiF = (ushort*)d_ws;                   // 32768 bf16 (64 KB)
    ushort* EwLoF = EwHiF + 32768;                   // 32768 bf16 (64 KB)
    float* Qh   = (float*)((char*)d_ws + 131072);    // N*128
    float* Kh   = Qh + (size_t)N * 128;
    float* Vh   = Kh + (size_t)N * 128;
    float* exO  = Vh + (size_t)N * 128;              // NE*8
    int* cnt      = (int*)(exO + (size_t)NE * 8);    // N
    int* rowstart = cnt + N;                         // N+1
    int* cursor   = rowstart + (N + 1);              // N
    int* elist    = cursor + N;                      // NE
    int* bsum     = elist + NE;                      // 64

    const int NB_SCAN = (N + 1023) / 1024;           // 49

    hipMemsetAsync(cnt, 0, (size_t)N * sizeof(int), stream);
    hipMemsetAsync(cursor, 0, (size_t)N * sizeof(int), stream);

    prep_w_kernel<<<16, 256, 0, stream>>>(Ew, EwHiF, EwLoF);

    qkv_rope_kernel<<<(N + NPB - 1) / NPB, 256, 0, stream>>>(
        x, rrwp, Qw, Qb, Kw, Kb, Vw, Vb, Wang, Qh, Kh, Vh);

    count_kernel<<<(NE + 255) / 256, 256, 0, stream>>>(dstI, cnt);
    block_scan_kernel<<<NB_SCAN, 1024, 0, stream>>>(cnt, rowstart, bsum);
    scan_totals_kernel<<<1, 64, 0, stream>>>(bsum, NB_SCAN);
    add_offsets_kernel<<<NB_SCAN, 1024, 0, stream>>>(bsum, rowstart);
    scatter_kernel<<<(NE + 255) / 256, 256, 0, stream>>>(dstI, rowstart, cursor, elist);

    edge_gemm_kernel<<<(NE + 63) / 64, 256, 0, stream>>>(
        edge_attr, srcI, dstI, Qh, Kh, EwHiF, EwLoF, Eb, wew, web, wE, exO);

    wv_kernel<<<(N + 1) / 2, 256, 0, stream>>>(
        srcI, elist, rowstart, Vh, exO, wV);
}

// Round 5
// 961.476 us; speedup vs baseline: 8.2261x; 1.3982x over previous
//
#include <hip/hip_runtime.h>
#include <hip/hip_bf16.h>
#include <math.h>

constexpr int N    = 50000;
constexpr int NE   = 500000;
constexpr int IN   = 128;
constexpr int H    = 8;
constexpr int D    = 16;
constexpr int DSEM = 4;
constexpr int KS   = 21;
constexpr float CLAMP = 5.0f;

typedef __attribute__((ext_vector_type(8))) __bf16 bf16x8;
typedef __attribute__((ext_vector_type(4))) float  f32x4;

__device__ inline f32x4 mfma16(bf16x8 a, bf16x8 b, f32x4 c) {
    return __builtin_amdgcn_mfma_f32_16x16x32_bf16(a, b, c, 0, 0, 0);
}

__device__ inline void split_bf16(float f, unsigned& hi, unsigned& lo) {
    unsigned u = __float_as_uint(f);
    hi = (u + 0x7FFFu + ((u >> 16) & 1u)) >> 16;
    float fl = f - __uint_as_float(hi << 16);
    unsigned ul = __float_as_uint(fl);
    lo = (ul + 0x7FFFu + ((ul >> 16) & 1u)) >> 16;
}

__device__ inline void split2(float a, float b, unsigned& hi, unsigned& lo) {
    unsigned ha, la, hb, lb;
    split_bf16(a, ha, la);
    split_bf16(b, hb, lb);
    hi = ha | (hb << 16);
    lo = la | (lb << 16);
}

// ---------------------------------------------------------------------------
// prep_w: split Ew (256x128) into bf16 hi/lo, fragment-linear.
// ---------------------------------------------------------------------------
__global__ __launch_bounds__(256) void prep_w_kernel(
    const float* __restrict__ Ew, ushort* __restrict__ EwHiF, ushort* __restrict__ EwLoF)
{
    int tid = blockIdx.x * 256 + threadIdx.x;          // 0..4095
    int l  = tid & 63;
    int ks = (tid >> 6) & 3;
    int ot = tid >> 8;
    int row = 16 * ot + (l & 15);
    int col = 32 * ks + 8 * (l >> 4);
    const float* src = Ew + (size_t)row * 128 + col;
    float4 f0 = *(const float4*)(src);
    float4 f1 = *(const float4*)(src + 4);
    unsigned H0,L0,H1,L1,H2,L2,H3,L3;
    split2(f0.x, f0.y, H0, L0);
    split2(f0.z, f0.w, H1, L1);
    split2(f1.x, f1.y, H2, L2);
    split2(f1.z, f1.w, H3, L3);
    *(uint4*)(EwHiF + (size_t)tid * 8) = make_uint4(H0, H1, H2, H3);
    *(uint4*)(EwLoF + (size_t)tid * 8) = make_uint4(L0, L1, L2, L3);
}

// ---------------------------------------------------------------------------
// prep_qkvw: split concat(Qw,Kw,Vw) (384x128) into bf16 hi/lo, frag-linear.
// tid: l=tid&63, ks=(tid>>6)&3, ot=tid>>8 (0..23); row=16*ot+(l&15).
// ---------------------------------------------------------------------------
__global__ __launch_bounds__(256) void prep_qkvw_kernel(
    const float* __restrict__ Qw, const float* __restrict__ Kw,
    const float* __restrict__ Vw,
    ushort* __restrict__ WHiF, ushort* __restrict__ WLoF)
{
    int tid = blockIdx.x * 256 + threadIdx.x;          // 0..6143
    int l  = tid & 63;
    int ks = (tid >> 6) & 3;
    int ot = tid >> 8;                                 // 0..23
    int row = 16 * ot + (l & 15);                      // 0..383
    int col = 32 * ks + 8 * (l >> 4);
    const float* wrow = (row < 128) ? (Qw + (size_t)row * 128)
                      : (row < 256) ? (Kw + (size_t)(row - 128) * 128)
                                    : (Vw + (size_t)(row - 256) * 128);
    const float* src = wrow + col;
    float4 f0 = *(const float4*)(src);
    float4 f1 = *(const float4*)(src + 4);
    unsigned H0,L0,H1,L1,H2,L2,H3,L3;
    split2(f0.x, f0.y, H0, L0);
    split2(f0.z, f0.w, H1, L1);
    split2(f1.x, f1.y, H2, L2);
    split2(f1.z, f1.w, H3, L3);
    *(uint4*)(WHiF + (size_t)tid * 8) = make_uint4(H0, H1, H2, H3);
    *(uint4*)(WLoF + (size_t)tid * 8) = make_uint4(L0, L1, L2, L3);
}

// ---------------------------------------------------------------------------
// K1: QKV projection via split-bf16 MFMA + fused RoPE epilogue.
// Block = 64 nodes x 384 outputs, 256 threads (4 waves x 6 o-tiles).
// LDS: W hi/lo (96 KB) + A hi/lo (16 KB) = 112 KB (GEMM phase);
//      sout 64x388 fp32 (97 KB, reuses W region) + srr/sc/ss (epilogue).
// ---------------------------------------------------------------------------
constexpr int QW_HI = 0;          // [24 ot][2 ks2][64 l][16 B] = 49152
constexpr int QW_LO = 49152;
constexpr int QA_HI = 98304;      // [4 g][2 ks2][64 l][16 B]  = 8192
constexpr int QA_LO = 106496;
constexpr int QSRR  = 114688;     // 64 x 24 fp32 = 6144
constexpr int QSC   = 120832;     // 64 x 48 fp32 = 12288
constexpr int QSS   = 133120;     // 64 x 48 fp32 = 12288  (end 145408)
constexpr int QSO_S = 388;        // sout stride (fp32 words)

__global__ __launch_bounds__(256) void qkv_mfma_kernel(
    const float* __restrict__ x, const float* __restrict__ rrwp,
    const ushort* __restrict__ WHiF, const ushort* __restrict__ WLoF,
    const float* __restrict__ Qb, const float* __restrict__ Kb,
    const float* __restrict__ Vb, const float* __restrict__ Wang,
    float* __restrict__ Qh, float* __restrict__ Kh, float* __restrict__ Vh)
{
    __shared__ __align__(16) char smem[145408];

    const int t    = threadIdx.x;
    const int wid  = t >> 6;
    const int lane = t & 63;
    const int nb0  = blockIdx.x * 64;

    float* srr  = (float*)(smem + QSRR);
    float* scc  = (float*)(smem + QSC);
    float* sss  = (float*)(smem + QSS);

    // stage rrwp rows (read long before first use; barriers below order it)
    for (int i = t; i < 64 * KS; i += 256) {
        int nl = i / KS, k = i % KS;
        int n = nb0 + nl;
        srr[nl * 24 + k] = (n < N) ? rrwp[(size_t)n * KS + k] : 0.0f;
    }

    f32x4 acc[4][6];
    #pragma unroll
    for (int g = 0; g < 4; g++)
        #pragma unroll
        for (int o = 0; o < 6; o++)
            acc[g][o] = (f32x4){0.f, 0.f, 0.f, 0.f};

    // A-staging mapping
    const int se   = t >> 2;
    const int sq   = t & 3;
    const int sr   = se & 15;
    const int sg   = se >> 4;
    const int sks2 = sq >> 1;
    const int slb  = 2 * (sq & 1);
    const int sn   = nb0 + se;
    const int abase = ((sg * 2 + sks2) * 64 + slb * 16 + sr) * 16;

    #pragma unroll 1
    for (int c = 0; c < 2; c++) {
        __syncthreads();
        // stage W chunk c: 24 ot x 128 float4 = 3072 per array
        #pragma unroll
        for (int r = 0; r < 12; r++) {
            int i = r * 256 + t;
            int ot = i >> 7;
            size_t src = (size_t)ot * 4096 + (size_t)c * 2048 + (size_t)(i & 127) * 16;
            *(float4*)(smem + QW_HI + i * 16) = *(const float4*)((const char*)WHiF + src);
            *(float4*)(smem + QW_LO + i * 16) = *(const float4*)((const char*)WLoF + src);
        }
        // stage A chunk c (x rows -> bf16 hi/lo frags)
        {
            float4 v0, v1, v2, v3;
            if (sn < N) {
                const float4* ar = (const float4*)(x + (size_t)sn * 128 + c * 64 + sq * 16);
                v0 = ar[0]; v1 = ar[1]; v2 = ar[2]; v3 = ar[3];
            } else {
                v0 = v1 = v2 = v3 = make_float4(0.f, 0.f, 0.f, 0.f);
            }
            unsigned H0,L0,H1,L1,H2,L2,H3,L3,H4,L4,H5,L5,H6,L6,H7,L7;
            split2(v0.x, v0.y, H0, L0); split2(v0.z, v0.w, H1, L1);
            split2(v1.x, v1.y, H2, L2); split2(v1.z, v1.w, H3, L3);
            split2(v2.x, v2.y, H4, L4); split2(v2.z, v2.w, H5, L5);
            split2(v3.x, v3.y, H6, L6); split2(v3.z, v3.w, H7, L7);
            *(uint4*)(smem + QA_HI + abase)       = make_uint4(H0, H1, H2, H3);
            *(uint4*)(smem + QA_HI + abase + 256) = make_uint4(H4, H5, H6, H7);
            *(uint4*)(smem + QA_LO + abase)       = make_uint4(L0, L1, L2, L3);
            *(uint4*)(smem + QA_LO + abase + 256) = make_uint4(L4, L5, L6, L7);
        }
        __syncthreads();

        #pragma unroll
        for (int ks2 = 0; ks2 < 2; ks2++) {
            bf16x8 Ah[4], Al[4];
            #pragma unroll
            for (int g = 0; g < 4; g++) {
                int off = ((g * 2 + ks2) * 64 + lane) * 16;
                Ah[g] = *(const bf16x8*)(smem + QA_HI + off);
                Al[g] = *(const bf16x8*)(smem + QA_LO + off);
            }
            #pragma unroll
            for (int otl = 0; otl < 6; otl++) {
                int woff = (((wid * 6 + otl) * 2 + ks2) * 64 + lane) * 16;
                bf16x8 Bh = *(const bf16x8*)(smem + QW_HI + woff);
                bf16x8 Bl = *(const bf16x8*)(smem + QW_LO + woff);
                #pragma unroll
                for (int g = 0; g < 4; g++) {
                    acc[g][otl] = mfma16(Ah[g], Bh, acc[g][otl]);
                    acc[g][otl] = mfma16(Al[g], Bh, acc[g][otl]);
                    acc[g][otl] = mfma16(Ah[g], Bl, acc[g][otl]);
                }
            }
        }
        __syncthreads();
    }

    // acc -> sout (+bias); reuses the W/A LDS region
    float* sout = (float*)smem;
    const int lr4 = (lane >> 4) * 4;
    const int lc  = lane & 15;
    #pragma unroll
    for (int otl = 0; otl < 6; otl++) {
        int o = (wid * 6 + otl) * 16 + lc;       // 0..383
        float bv = (o < 128) ? Qb[o] : (o < 256) ? Kb[o - 128] : Vb[o - 256];
        #pragma unroll
        for (int g = 0; g < 4; g++) {
            int e = 16 * g + lr4;
            #pragma unroll
            for (int jr = 0; jr < 4; jr++)
                sout[(e + jr) * QSO_S + o] = acc[g][otl][jr] + bv;
        }
    }
    __syncthreads();

    // angles: 64 nodes x 48 (h,r)
    for (int i = t; i < 64 * 48; i += 256) {
        int nl = i / 48, a = i % 48;
        int h = a / 6, r = a % 6;
        float av = 0.0f;
        #pragma unroll
        for (int k = 0; k < KS; k++)
            av = fmaf(srr[nl * 24 + k], Wang[(size_t)(h * KS + k) * 6 + r], av);
        float sv, cv;
        sincosf(av, &sv, &cv);
        scc[nl * 48 + a] = cv;
        sss[nl * 48 + a] = sv;
    }
    __syncthreads();

    // rotate + write out
    for (int i = t; i < 64 * 384; i += 256) {
        int nl = i / 384, o = i % 384;
        int n = nb0 + nl;
        if (n >= N) continue;
        int mat = o >> 7;
        int oo  = o & 127;
        int h = oo >> 4, d = oo & 15;
        float val;
        if (mat == 2 || d < DSEM) {
            val = sout[nl * QSO_S + o];
        } else {
            int i2 = (d - DSEM) >> 1;
            float cv = scc[nl * 48 + h * 6 + i2];
            float sv = sss[nl * 48 + h * 6 + i2];
            int base = (mat << 7) + h * 16 + DSEM + 2 * i2;
            float xe = sout[nl * QSO_S + base];
            float xo = sout[nl * QSO_S + base + 1];
            val = ((d & 1) == 0) ? (xe * cv - xo * sv) : (xe * sv + xo * cv);
        }
        float* dp = (mat == 0) ? Qh : (mat == 1) ? Kh : Vh;
        dp[(size_t)n * 128 + oo] = val;
    }
}

// ---------------------------------------------------------------------------
// K2: split-bf16 MFMA edge GEMM (unchanged from round 4)
// ---------------------------------------------------------------------------
constexpr int WHI_OFF = 0;
constexpr int WLO_OFF = 32768;
constexpr int AHI_OFF = 65536;
constexpr int ALO_OFF = 73728;
constexpr int SO_STRIDE = 268;

__global__ __launch_bounds__(256, 2) void edge_gemm_kernel(
    const float* __restrict__ edge_attr,
    const int* __restrict__ srcI, const int* __restrict__ dstI,
    const float* __restrict__ Qh, const float* __restrict__ Kh,
    const ushort* __restrict__ EwHiF, const ushort* __restrict__ EwLoF,
    const float* __restrict__ Eb,
    const float* __restrict__ wew, const float* __restrict__ web,
    float* __restrict__ wE, float* __restrict__ exOut)
{
    __shared__ __align__(16) char smem[81920];

    const int t    = threadIdx.x;
    const int wid  = t >> 6;
    const int lane = t & 63;
    const int eb0  = blockIdx.x * 64;

    f32x4 acc[4][4];
    #pragma unroll
    for (int g = 0; g < 4; g++)
        #pragma unroll
        for (int o = 0; o < 4; o++)
            acc[g][o] = (f32x4){0.f, 0.f, 0.f, 0.f};

    const int se   = t >> 2;
    const int sq   = t & 3;
    const int sr   = se & 15;
    const int sg   = se >> 4;
    const int sks2 = sq >> 1;
    const int slb  = 2 * (sq & 1);
    const int sge  = eb0 + se;
    const int abase = ((sg * 2 + sks2) * 64 + slb * 16 + sr) * 16;

    #pragma unroll 1
    for (int c = 0; c < 2; c++) {
        #pragma unroll
        for (int r = 0; r < 8; r++) {
            int i = r * 256 + t;
            int ot = i >> 7;
            size_t src = (size_t)ot * 4096 + (size_t)c * 2048 + (size_t)(i & 127) * 16;
            *(float4*)(smem + WHI_OFF + i * 16) = *(const float4*)((const char*)EwHiF + src);
            *(float4*)(smem + WLO_OFF + i * 16) = *(const float4*)((const char*)EwLoF + src);
        }
        {
            float4 v0, v1, v2, v3;
            if (sge < NE) {
                const float4* ar = (const float4*)(edge_attr + (size_t)sge * 128 + c * 64 + sq * 16);
                v0 = ar[0]; v1 = ar[1]; v2 = ar[2]; v3 = ar[3];
            } else {
                v0 = v1 = v2 = v3 = make_float4(0.f, 0.f, 0.f, 0.f);
            }
            unsigned H0,L0,H1,L1,H2,L2,H3,L3,H4,L4,H5,L5,H6,L6,H7,L7;
            split2(v0.x, v0.y, H0, L0); split2(v0.z, v0.w, H1, L1);
            split2(v1.x, v1.y, H2, L2); split2(v1.z, v1.w, H3, L3);
            split2(v2.x, v2.y, H4, L4); split2(v2.z, v2.w, H5, L5);
            split2(v3.x, v3.y, H6, L6); split2(v3.z, v3.w, H7, L7);
            *(uint4*)(smem + AHI_OFF + abase)       = make_uint4(H0, H1, H2, H3);
            *(uint4*)(smem + AHI_OFF + abase + 256) = make_uint4(H4, H5, H6, H7);
            *(uint4*)(smem + ALO_OFF + abase)       = make_uint4(L0, L1, L2, L3);
            *(uint4*)(smem + ALO_OFF + abase + 256) = make_uint4(L4, L5, L6, L7);
        }
        __syncthreads();

        #pragma unroll
        for (int ks2 = 0; ks2 < 2; ks2++) {
            bf16x8 Ah[4], Al[4];
            #pragma unroll
            for (int g = 0; g < 4; g++) {
                int off = ((g * 2 + ks2) * 64 + lane) * 16;
                Ah[g] = *(const bf16x8*)(smem + AHI_OFF + off);
                Al[g] = *(const bf16x8*)(smem + ALO_OFF + off);
            }
            #pragma unroll
            for (int otl = 0; otl < 4; otl++) {
                int woff = (((wid * 4 + otl) * 2 + ks2) * 64 + lane) * 16;
                bf16x8 Bh = *(const bf16x8*)(smem + WHI_OFF + woff);
                bf16x8 Bl = *(const bf16x8*)(smem + WLO_OFF + woff);
                #pragma unroll
                for (int g = 0; g < 4; g++) {
                    acc[g][otl] = mfma16(Ah[g], Bh, acc[g][otl]);
                    acc[g][otl] = mfma16(Al[g], Bh, acc[g][otl]);
                    acc[g][otl] = mfma16(Ah[g], Bl, acc[g][otl]);
                }
            }
        }
        __syncthreads();
    }

    float* sOut = (float*)smem;
    const int lr4 = (lane >> 4) * 4;
    const int lc  = lane & 15;
    #pragma unroll
    for (int otl = 0; otl < 4; otl++) {
        int o = (wid * 4 + otl) * 16 + lc;
        float ebv = Eb[o];
        #pragma unroll
        for (int g = 0; g < 4; g++) {
            int e = 16 * g + lr4;
            #pragma unroll
            for (int jr = 0; jr < 4; jr++)
                sOut[(e + jr) * SO_STRIDE + o] = acc[g][otl][jr] + ebv;
        }
    }
    __syncthreads();

    const int e_l = t >> 2;
    const int hp  = t & 3;
    const int ge  = eb0 + e_l;
    if (ge < NE) {
        const int s  = srcI[ge];
        const int dd = dstI[ge];
        const int h0 = 2 * hp, h1 = 2 * hp + 1;

        const float4* ar = (const float4*)(edge_attr + (size_t)ge * 128);
        const float4* w0 = (const float4*)(wew + (size_t)h0 * 128);
        const float4* w1 = (const float4*)(wew + (size_t)h1 * 128);
        float b0 = 0.f, b1 = 0.f;
        #pragma unroll
        for (int k = 0; k < 32; k++) {
            float4 a = ar[k], u = w0[k], v = w1[k];
            b0 = fmaf(a.x, u.x, b0); b0 = fmaf(a.y, u.y, b0);
            b0 = fmaf(a.z, u.z, b0); b0 = fmaf(a.w, u.w, b0);
            b1 = fmaf(a.x, v.x, b1); b1 = fmaf(a.y, v.y, b1);
            b1 = fmaf(a.z, v.z, b1); b1 = fmaf(a.w, v.w, b1);
        }
        float ebias0 = b0 + web[h0];
        float ebias1 = b1 + web[h1];

        const float4* K4 = (const float4*)(Kh + (size_t)s  * 128);
        const float4* Q4 = (const float4*)(Qh + (size_t)dd * 128);
        const float inv_s4  = 0.5f;
        const float inv_s12 = 0.28867513459481288f;
        #pragma unroll
        for (int hi = 0; hi < 2; hi++) {
            int hh = 2 * hp + hi;
            float eb = (hi == 0) ? ebias0 : ebias1;
            float4 kf[4], qf[4];
            #pragma unroll
            for (int j = 0; j < 4; j++) { kf[j] = K4[hh * 4 + j]; qf[j] = Q4[hh * 4 + j]; }
            float sem = kf[0].x*qf[0].x + kf[0].y*qf[0].y + kf[0].z*qf[0].z + kf[0].w*qf[0].w;
            float stl = 0.0f;
            #pragma unroll
            for (int j = 1; j < 4; j++)
                stl += kf[j].x*qf[j].x + kf[j].y*qf[j].y + kf[j].z*qf[j].z + kf[j].w*qf[j].w;
            float logit = sem * inv_s4 + stl * inv_s12 + eb;
            logit = fminf(fmaxf(logit, -CLAMP), CLAMP);
            float ex = __expf(logit);
            exOut[(size_t)ge * 8 + hh] = ex;
            const float* srow = sOut + e_l * SO_STRIDE + hh * 32;
            #pragma unroll
            for (int u = 0; u < 4; u++) {
                float4 A = *(const float4*)(srow + 4 * u);
                float4 B = *(const float4*)(srow + 16 + 4 * u);
                float4 kq = make_float4(kf[u].x + qf[u].x, kf[u].y + qf[u].y,
                                        kf[u].z + qf[u].z, kf[u].w + qf[u].w);
                float4 o;
                float v;
                v = kq.x * A.x; o.x = copysignf(sqrtf(fabsf(v)), v) + B.x;
                v = kq.y * A.y; o.y = copysignf(sqrtf(fabsf(v)), v) + B.y;
                v = kq.z * A.z; o.z = copysignf(sqrtf(fabsf(v)), v) + B.z;
                v = kq.w * A.w; o.w = copysignf(sqrtf(fabsf(v)), v) + B.w;
                *(float4*)(wE + (size_t)ge * 128 + hh * 16 + 4 * u) = o;
            }
        }
    }
}

// ---------------------------------------------------------------------------
// CSR build (unchanged)
// ---------------------------------------------------------------------------
__global__ __launch_bounds__(256) void count_kernel(
    const int* __restrict__ dstI, int* __restrict__ cnt)
{
    int e = blockIdx.x * 256 + threadIdx.x;
    if (e < NE) atomicAdd(&cnt[dstI[e]], 1);
}

__global__ __launch_bounds__(1024) void block_scan_kernel(
    const int* __restrict__ cnt, int* __restrict__ rowstart, int* __restrict__ bsum)
{
    __shared__ int sbuf[1024];
    const int b = blockIdx.x, t = threadIdx.x;
    const int i = b * 1024 + t;
    sbuf[t] = (i < N) ? cnt[i] : 0;
    __syncthreads();
    for (int off = 1; off < 1024; off <<= 1) {
        int xv = sbuf[t];
        int yv = (t >= off) ? sbuf[t - off] : 0;
        __syncthreads();
        sbuf[t] = xv + yv;
        __syncthreads();
    }
    if (i < N) rowstart[i + 1] = sbuf[t];
    if (t == 1023) bsum[b] = sbuf[1023];
}

__global__ void scan_totals_kernel(int* __restrict__ bsum, int nb)
{
    if (threadIdx.x == 0 && blockIdx.x == 0) {
        int run = 0;
        for (int b = 0; b < nb; b++) { int v = bsum[b]; bsum[b] = run; run += v; }
    }
}

__global__ __launch_bounds__(1024) void add_offsets_kernel(
    const int* __restrict__ bsum, int* __restrict__ rowstart)
{
    const int b = blockIdx.x, t = threadIdx.x;
    const int i = b * 1024 + t;
    if (i < N) rowstart[i + 1] += bsum[b];
    if (b == 0 && t == 0) rowstart[0] = 0;
}

__global__ __launch_bounds__(256) void scatter_kernel(
    const int* __restrict__ dstI, const int* __restrict__ rowstart,
    int* __restrict__ cursor, int* __restrict__ elist)
{
    int e = blockIdx.x * 256 + threadIdx.x;
    if (e >= NE) return;
    int d = dstI[e];
    int pos = atomicAdd(&cursor[d], 1);
    elist[rowstart[d] + pos] = e;
}

// ---------------------------------------------------------------------------
// K3: gather-based wV (unchanged)
// ---------------------------------------------------------------------------
__global__ __launch_bounds__(256) void wv_kernel(
    const int* __restrict__ srcI, const int* __restrict__ elist,
    const int* __restrict__ rowstart, const float* __restrict__ Vh,
    const float* __restrict__ exOut, float* __restrict__ wV)
{
    const int dd = blockIdx.x * 2 + (threadIdx.x >> 7);
    const int o  = threadIdx.x & 127;
    if (dd >= N) return;
    const int h  = o >> 4;
    const int st = rowstart[dd];
    const int en = rowstart[dd + 1];
    float den = 0.0f, num = 0.0f;
    for (int i = st; i < en; i++) {
        int e = elist[i];
        float ex = exOut[(size_t)e * 8 + h];
        int s = srcI[e];
        num = fmaf(Vh[(size_t)s * 128 + o], ex, num);
        den += ex;
    }
    wV[(size_t)dd * 128 + o] = num / (den + 1e-16f);
}

// ---------------------------------------------------------------------------
extern "C" void kernel_launch(void* const* d_in, const int* in_sizes, int n_in,
                              void* d_out, int out_size, void* d_ws, size_t ws_size,
                              hipStream_t stream)
{
    const float* x         = (const float*)d_in[0];
    const int*   edge_idx  = (const int*)d_in[1];
    const float* rrwp      = (const float*)d_in[2];
    const float* edge_attr = (const float*)d_in[3];
    const float* Qw        = (const float*)d_in[4];
    const float* Qb        = (const float*)d_in[5];
    const float* Kw        = (const float*)d_in[6];
    const float* Kb        = (const float*)d_in[7];
    const float* Vw        = (const float*)d_in[8];
    const float* Vb        = (const float*)d_in[9];
    const float* Ew        = (const float*)d_in[10];
    const float* Eb        = (const float*)d_in[11];
    const float* wew       = (const float*)d_in[12];
    const float* web       = (const float*)d_in[13];
    const float* Wang      = (const float*)d_in[14];

    const int* srcI = edge_idx;
    const int* dstI = edge_idx + NE;

    float* wV = (float*)d_out;                       // N * 128
    float* wE = wV + (size_t)N * 128;                // NE * 128

    // workspace layout
    ushort* EwHiF = (ushort*)d_ws;                   // 32768 bf16
    ushort* EwLoF = EwHiF + 32768;                   // 32768
    ushort* QWHiF = EwLoF + 32768;                   // 49152
    ushort* QWLoF = QWHiF + 49152;                   // 49152
    float* Qh   = (float*)((char*)d_ws + 131072 + 196608);
    float* Kh   = Qh + (size_t)N * 128;
    float* Vh   = Kh + (size_t)N * 128;
    float* exO  = Vh + (size_t)N * 128;              // NE*8
    int* cnt      = (int*)(exO + (size_t)NE * 8);    // N
    int* rowstart = cnt + N;                         // N+1
    int* cursor   = rowstart + (N + 1);              // N
    int* elist    = cursor + N;                      // NE
    int* bsum     = elist + NE;                      // 64

    const int NB_SCAN = (N + 1023) / 1024;           // 49

    hipMemsetAsync(cnt, 0, (size_t)N * sizeof(int), stream);
    hipMemsetAsync(cursor, 0, (size_t)N * sizeof(int), stream);

    prep_w_kernel<<<16, 256, 0, stream>>>(Ew, EwHiF, EwLoF);
    prep_qkvw_kernel<<<24, 256, 0, stream>>>(Qw, Kw, Vw, QWHiF, QWLoF);

    qkv_mfma_kernel<<<(N + 63) / 64, 256, 0, stream>>>(
        x, rrwp, QWHiF, QWLoF, Qb, Kb, Vb, Wang, Qh, Kh, Vh);

    count_kernel<<<(NE + 255) / 256, 256, 0, stream>>>(dstI, cnt);
    block_scan_kernel<<<NB_SCAN, 1024, 0, stream>>>(cnt, rowstart, bsum);
    scan_totals_kernel<<<1, 64, 0, stream>>>(bsum, NB_SCAN);
    add_offsets_kernel<<<NB_SCAN, 1024, 0, stream>>>(bsum, rowstart);
    scatter_kernel<<<(NE + 255) / 256, 256, 0, stream>>>(dstI, rowstart, cursor, elist);

    edge_gemm_kernel<<<(NE + 63) / 64, 256, 0, stream>>>(
        edge_attr, srcI, dstI, Qh, Kh, EwHiF, EwLoF, Eb, wew, web, wE, exO);

    wv_kernel<<<(N + 1) / 2, 256, 0, stream>>>(
        srcI, elist, rowstart, Vh, exO, wV);
}

// Round 6
// 738.172 us; speedup vs baseline: 10.7146x; 1.3025x over previous
//
#include <hip/hip_runtime.h>
#include <hip/hip_bf16.h>
#include <math.h>

constexpr int N    = 50000;
constexpr int NE   = 500000;
constexpr int IN   = 128;
constexpr int H    = 8;
constexpr int D    = 16;
constexpr int DSEM = 4;
constexpr int KS   = 21;
constexpr float CLAMP = 5.0f;

typedef __attribute__((ext_vector_type(8))) __bf16 bf16x8;
typedef __attribute__((ext_vector_type(4))) float  f32x4;

__device__ inline f32x4 mfma16(bf16x8 a, bf16x8 b, f32x4 c) {
    return __builtin_amdgcn_mfma_f32_16x16x32_bf16(a, b, c, 0, 0, 0);
}

__device__ inline void split_bf16(float f, unsigned& hi, unsigned& lo) {
    unsigned u = __float_as_uint(f);
    hi = (u + 0x7FFFu + ((u >> 16) & 1u)) >> 16;
    float fl = f - __uint_as_float(hi << 16);
    unsigned ul = __float_as_uint(fl);
    lo = (ul + 0x7FFFu + ((ul >> 16) & 1u)) >> 16;
}

__device__ inline void split2(float a, float b, unsigned& hi, unsigned& lo) {
    unsigned ha, la, hb, lb;
    split_bf16(a, ha, la);
    split_bf16(b, hb, lb);
    hi = ha | (hb << 16);
    lo = la | (lb << 16);
}

// ---------------------------------------------------------------------------
// prep_w: split [Ew (256 rows); wew (8 rows); zeros (8 rows)] = 272x128 into
// bf16 hi/lo, fragment-linear: elem ((ot*4+ks)*64+l)*8+j <- row 16*ot+(l&15),
// col 32*ks + 8*(l>>4) + j.  17 o-tiles.
// ---------------------------------------------------------------------------
__global__ __launch_bounds__(256) void prep_w_kernel(
    const float* __restrict__ Ew, const float* __restrict__ wew,
    ushort* __restrict__ EwHiF, ushort* __restrict__ EwLoF)
{
    int tid = blockIdx.x * 256 + threadIdx.x;          // 0..4351
    int l  = tid & 63;
    int ks = (tid >> 6) & 3;
    int ot = tid >> 8;                                 // 0..16
    int row = 16 * ot + (l & 15);
    int col = 32 * ks + 8 * (l >> 4);
    float4 f0, f1;
    if (row < 256) {
        const float* src = Ew + (size_t)row * 128 + col;
        f0 = *(const float4*)(src);
        f1 = *(const float4*)(src + 4);
    } else if (row < 264) {
        const float* src = wew + (size_t)(row - 256) * 128 + col;
        f0 = *(const float4*)(src);
        f1 = *(const float4*)(src + 4);
    } else {
        f0 = f1 = make_float4(0.f, 0.f, 0.f, 0.f);
    }
    unsigned H0,L0,H1,L1,H2,L2,H3,L3;
    split2(f0.x, f0.y, H0, L0);
    split2(f0.z, f0.w, H1, L1);
    split2(f1.x, f1.y, H2, L2);
    split2(f1.z, f1.w, H3, L3);
    *(uint4*)(EwHiF + (size_t)tid * 8) = make_uint4(H0, H1, H2, H3);
    *(uint4*)(EwLoF + (size_t)tid * 8) = make_uint4(L0, L1, L2, L3);
}

// ---------------------------------------------------------------------------
// prep_qkvw: split concat(Qw,Kw,Vw) (384x128) into bf16 hi/lo, frag-linear.
// ---------------------------------------------------------------------------
__global__ __launch_bounds__(256) void prep_qkvw_kernel(
    const float* __restrict__ Qw, const float* __restrict__ Kw,
    const float* __restrict__ Vw,
    ushort* __restrict__ WHiF, ushort* __restrict__ WLoF)
{
    int tid = blockIdx.x * 256 + threadIdx.x;          // 0..6143
    int l  = tid & 63;
    int ks = (tid >> 6) & 3;
    int ot = tid >> 8;                                 // 0..23
    int row = 16 * ot + (l & 15);                      // 0..383
    int col = 32 * ks + 8 * (l >> 4);
    const float* wrow = (row < 128) ? (Qw + (size_t)row * 128)
                      : (row < 256) ? (Kw + (size_t)(row - 128) * 128)
                                    : (Vw + (size_t)(row - 256) * 128);
    const float* src = wrow + col;
    float4 f0 = *(const float4*)(src);
    float4 f1 = *(const float4*)(src + 4);
    unsigned H0,L0,H1,L1,H2,L2,H3,L3;
    split2(f0.x, f0.y, H0, L0);
    split2(f0.z, f0.w, H1, L1);
    split2(f1.x, f1.y, H2, L2);
    split2(f1.z, f1.w, H3, L3);
    *(uint4*)(WHiF + (size_t)tid * 8) = make_uint4(H0, H1, H2, H3);
    *(uint4*)(WLoF + (size_t)tid * 8) = make_uint4(L0, L1, L2, L3);
}

// ---------------------------------------------------------------------------
// K1: QKV projection via split-bf16 MFMA + fused RoPE epilogue (unchanged).
// ---------------------------------------------------------------------------
constexpr int QW_HI = 0;
constexpr int QW_LO = 49152;
constexpr int QA_HI = 98304;
constexpr int QA_LO = 106496;
constexpr int QSRR  = 114688;
constexpr int QSC   = 120832;
constexpr int QSS   = 133120;
constexpr int QSO_S = 388;

__global__ __launch_bounds__(256) void qkv_mfma_kernel(
    const float* __restrict__ x, const float* __restrict__ rrwp,
    const ushort* __restrict__ WHiF, const ushort* __restrict__ WLoF,
    const float* __restrict__ Qb, const float* __restrict__ Kb,
    const float* __restrict__ Vb, const float* __restrict__ Wang,
    float* __restrict__ Qh, float* __restrict__ Kh, float* __restrict__ Vh)
{
    __shared__ __align__(16) char smem[145408];

    const int t    = threadIdx.x;
    const int wid  = t >> 6;
    const int lane = t & 63;
    const int nb0  = blockIdx.x * 64;

    float* srr  = (float*)(smem + QSRR);
    float* scc  = (float*)(smem + QSC);
    float* sss  = (float*)(smem + QSS);

    for (int i = t; i < 64 * KS; i += 256) {
        int nl = i / KS, k = i % KS;
        int n = nb0 + nl;
        srr[nl * 24 + k] = (n < N) ? rrwp[(size_t)n * KS + k] : 0.0f;
    }

    f32x4 acc[4][6];
    #pragma unroll
    for (int g = 0; g < 4; g++)
        #pragma unroll
        for (int o = 0; o < 6; o++)
            acc[g][o] = (f32x4){0.f, 0.f, 0.f, 0.f};

    const int se   = t >> 2;
    const int sq   = t & 3;
    const int sr   = se & 15;
    const int sg   = se >> 4;
    const int sks2 = sq >> 1;
    const int slb  = 2 * (sq & 1);
    const int sn   = nb0 + se;
    const int abase = ((sg * 2 + sks2) * 64 + slb * 16 + sr) * 16;

    #pragma unroll 1
    for (int c = 0; c < 2; c++) {
        __syncthreads();
        #pragma unroll
        for (int r = 0; r < 12; r++) {
            int i = r * 256 + t;
            int ot = i >> 7;
            size_t src = (size_t)ot * 4096 + (size_t)c * 2048 + (size_t)(i & 127) * 16;
            *(float4*)(smem + QW_HI + i * 16) = *(const float4*)((const char*)WHiF + src);
            *(float4*)(smem + QW_LO + i * 16) = *(const float4*)((const char*)WLoF + src);
        }
        {
            float4 v0, v1, v2, v3;
            if (sn < N) {
                const float4* ar = (const float4*)(x + (size_t)sn * 128 + c * 64 + sq * 16);
                v0 = ar[0]; v1 = ar[1]; v2 = ar[2]; v3 = ar[3];
            } else {
                v0 = v1 = v2 = v3 = make_float4(0.f, 0.f, 0.f, 0.f);
            }
            unsigned H0,L0,H1,L1,H2,L2,H3,L3,H4,L4,H5,L5,H6,L6,H7,L7;
            split2(v0.x, v0.y, H0, L0); split2(v0.z, v0.w, H1, L1);
            split2(v1.x, v1.y, H2, L2); split2(v1.z, v1.w, H3, L3);
            split2(v2.x, v2.y, H4, L4); split2(v2.z, v2.w, H5, L5);
            split2(v3.x, v3.y, H6, L6); split2(v3.z, v3.w, H7, L7);
            *(uint4*)(smem + QA_HI + abase)       = make_uint4(H0, H1, H2, H3);
            *(uint4*)(smem + QA_HI + abase + 256) = make_uint4(H4, H5, H6, H7);
            *(uint4*)(smem + QA_LO + abase)       = make_uint4(L0, L1, L2, L3);
            *(uint4*)(smem + QA_LO + abase + 256) = make_uint4(L4, L5, L6, L7);
        }
        __syncthreads();

        #pragma unroll
        for (int ks2 = 0; ks2 < 2; ks2++) {
            bf16x8 Ah[4], Al[4];
            #pragma unroll
            for (int g = 0; g < 4; g++) {
                int off = ((g * 2 + ks2) * 64 + lane) * 16;
                Ah[g] = *(const bf16x8*)(smem + QA_HI + off);
                Al[g] = *(const bf16x8*)(smem + QA_LO + off);
            }
            #pragma unroll
            for (int otl = 0; otl < 6; otl++) {
                int woff = (((wid * 6 + otl) * 2 + ks2) * 64 + lane) * 16;
                bf16x8 Bh = *(const bf16x8*)(smem + QW_HI + woff);
                bf16x8 Bl = *(const bf16x8*)(smem + QW_LO + woff);
                #pragma unroll
                for (int g = 0; g < 4; g++) {
                    acc[g][otl] = mfma16(Ah[g], Bh, acc[g][otl]);
                    acc[g][otl] = mfma16(Al[g], Bh, acc[g][otl]);
                    acc[g][otl] = mfma16(Ah[g], Bl, acc[g][otl]);
                }
            }
        }
        __syncthreads();
    }

    float* sout = (float*)smem;
    const int lr4 = (lane >> 4) * 4;
    const int lc  = lane & 15;
    #pragma unroll
    for (int otl = 0; otl < 6; otl++) {
        int o = (wid * 6 + otl) * 16 + lc;
        float bv = (o < 128) ? Qb[o] : (o < 256) ? Kb[o - 128] : Vb[o - 256];
        #pragma unroll
        for (int g = 0; g < 4; g++) {
            int e = 16 * g + lr4;
            #pragma unroll
            for (int jr = 0; jr < 4; jr++)
                sout[(e + jr) * QSO_S + o] = acc[g][otl][jr] + bv;
        }
    }
    __syncthreads();

    for (int i = t; i < 64 * 48; i += 256) {
        int nl = i / 48, a = i % 48;
        int h = a / 6, r = a % 6;
        float av = 0.0f;
        #pragma unroll
        for (int k = 0; k < KS; k++)
            av = fmaf(srr[nl * 24 + k], Wang[(size_t)(h * KS + k) * 6 + r], av);
        float sv, cv;
        sincosf(av, &sv, &cv);
        scc[nl * 48 + a] = cv;
        sss[nl * 48 + a] = sv;
    }
    __syncthreads();

    for (int i = t; i < 64 * 384; i += 256) {
        int nl = i / 384, o = i % 384;
        int n = nb0 + nl;
        if (n >= N) continue;
        int mat = o >> 7;
        int oo  = o & 127;
        int h = oo >> 4, d = oo & 15;
        float val;
        if (mat == 2 || d < DSEM) {
            val = sout[nl * QSO_S + o];
        } else {
            int i2 = (d - DSEM) >> 1;
            float cv = scc[nl * 48 + h * 6 + i2];
            float sv = sss[nl * 48 + h * 6 + i2];
            int base = (mat << 7) + h * 16 + DSEM + 2 * i2;
            float xe = sout[nl * QSO_S + base];
            float xo = sout[nl * QSO_S + base + 1];
            val = ((d & 1) == 0) ? (xe * cv - xo * sv) : (xe * sv + xo * cv);
        }
        float* dp = (mat == 0) ? Qh : (mat == 1) ? Kh : Vh;
        dp[(size_t)n * 128 + oo] = val;
    }
}

// ---------------------------------------------------------------------------
// K2: split-bf16 MFMA edge GEMM, v2.
//  - W fragments loaded DIRECTLY global->registers (L2-resident, wave-private)
//  - e_bias computed as the 17th MFMA o-tile (wave 0) -> sBias
//  - edge_attr prefetched once for both K-chunks
//  - LDS: A hi/lo 16 KB (GEMM phase, overlaps sOut) ; sOut 64x292 + sBias
// ---------------------------------------------------------------------------
constexpr int AHI_OFF = 0;        // [4 g][2 ks2][64 l][16 B] = 8192
constexpr int ALO_OFF = 8192;
constexpr int SO_S    = 292;      // sOut row stride (words); head stride 36
constexpr int SH_S    = 36;
constexpr int SBIAS_OFF = 64 * SO_S * 4;        // 74752
constexpr int EDG_LDS   = SBIAS_OFF + 64 * 12 * 4;  // 77824

__global__ __launch_bounds__(256, 2) void edge_gemm_kernel(
    const float* __restrict__ edge_attr,
    const int* __restrict__ srcI, const int* __restrict__ dstI,
    const float* __restrict__ Qh, const float* __restrict__ Kh,
    const ushort* __restrict__ EwHiF, const ushort* __restrict__ EwLoF,
    const float* __restrict__ Eb, const float* __restrict__ web,
    float* __restrict__ wE, float* __restrict__ exOut)
{
    __shared__ __align__(16) char smem[EDG_LDS];

    const int t    = threadIdx.x;
    const int wid  = t >> 6;
    const int lane = t & 63;
    const int eb0  = blockIdx.x * 64;

    // ---- early prefetch: edge_attr rows (both chunks) + epilogue indices ----
    const int se   = t >> 2;
    const int sq   = t & 3;
    const int sge  = eb0 + se;
    float4 av[8];
    {
        if (sge < NE) {
            const float4* ar = (const float4*)(edge_attr + (size_t)sge * 128 + sq * 16);
            #pragma unroll
            for (int j = 0; j < 4; j++) av[j] = ar[j];
            #pragma unroll
            for (int j = 0; j < 4; j++) av[4 + j] = ar[16 + j];
        } else {
            #pragma unroll
            for (int j = 0; j < 8; j++) av[j] = make_float4(0.f, 0.f, 0.f, 0.f);
        }
    }
    const int e_l = t >> 2;
    const int geC = (eb0 + e_l < NE) ? (eb0 + e_l) : (NE - 1);
    const int sIdx = srcI[geC];
    const int dIdx = dstI[geC];

    f32x4 acc[4][4];
    #pragma unroll
    for (int g = 0; g < 4; g++)
        #pragma unroll
        for (int o = 0; o < 4; o++)
            acc[g][o] = (f32x4){0.f, 0.f, 0.f, 0.f};
    f32x4 accb[4];
    #pragma unroll
    for (int g = 0; g < 4; g++) accb[g] = (f32x4){0.f, 0.f, 0.f, 0.f};

    const int sr   = se & 15;
    const int sg   = se >> 4;
    const int sks2 = sq >> 1;
    const int slb  = 2 * (sq & 1);
    const int abase = ((sg * 2 + sks2) * 64 + slb * 16 + sr) * 16;

    #pragma unroll 1
    for (int c = 0; c < 2; c++) {
        // stage A chunk c from prefetched regs
        {
            const float4* vv = av + c * 4;
            unsigned H0,L0,H1,L1,H2,L2,H3,L3,H4,L4,H5,L5,H6,L6,H7,L7;
            split2(vv[0].x, vv[0].y, H0, L0); split2(vv[0].z, vv[0].w, H1, L1);
            split2(vv[1].x, vv[1].y, H2, L2); split2(vv[1].z, vv[1].w, H3, L3);
            split2(vv[2].x, vv[2].y, H4, L4); split2(vv[2].z, vv[2].w, H5, L5);
            split2(vv[3].x, vv[3].y, H6, L6); split2(vv[3].z, vv[3].w, H7, L7);
            *(uint4*)(smem + AHI_OFF + abase)       = make_uint4(H0, H1, H2, H3);
            *(uint4*)(smem + AHI_OFF + abase + 256) = make_uint4(H4, H5, H6, H7);
            *(uint4*)(smem + ALO_OFF + abase)       = make_uint4(L0, L1, L2, L3);
            *(uint4*)(smem + ALO_OFF + abase + 256) = make_uint4(L4, L5, L6, L7);
        }
        __syncthreads();

        #pragma unroll
        for (int ks2 = 0; ks2 < 2; ks2++) {
            // W fragments: direct global loads (L2-resident frag-linear array)
            bf16x8 Wh[4], Wl[4];
            #pragma unroll
            for (int otl = 0; otl < 4; otl++) {
                int ot = wid * 4 + otl;
                size_t woff = (size_t)(((ot * 4 + c * 2 + ks2) * 64 + lane)) * 16;
                Wh[otl] = *(const bf16x8*)((const char*)EwHiF + woff);
                Wl[otl] = *(const bf16x8*)((const char*)EwLoF + woff);
            }
            bf16x8 Bbh, Bbl;
            if (wid == 0) {
                size_t woff = (size_t)(((16 * 4 + c * 2 + ks2) * 64 + lane)) * 16;
                Bbh = *(const bf16x8*)((const char*)EwHiF + woff);
                Bbl = *(const bf16x8*)((const char*)EwLoF + woff);
            }
            bf16x8 Ah[4], Al[4];
            #pragma unroll
            for (int g = 0; g < 4; g++) {
                int off = ((g * 2 + ks2) * 64 + lane) * 16;
                Ah[g] = *(const bf16x8*)(smem + AHI_OFF + off);
                Al[g] = *(const bf16x8*)(smem + ALO_OFF + off);
            }
            #pragma unroll
            for (int otl = 0; otl < 4; otl++) {
                #pragma unroll
                for (int g = 0; g < 4; g++) {
                    acc[g][otl] = mfma16(Ah[g], Wh[otl], acc[g][otl]);
                    acc[g][otl] = mfma16(Al[g], Wh[otl], acc[g][otl]);
                    acc[g][otl] = mfma16(Ah[g], Wl[otl], acc[g][otl]);
                }
            }
            if (wid == 0) {
                #pragma unroll
                for (int g = 0; g < 4; g++) {
                    accb[g] = mfma16(Ah[g], Bbh, accb[g]);
                    accb[g] = mfma16(Al[g], Bbh, accb[g]);
                    accb[g] = mfma16(Ah[g], Bbl, accb[g]);
                }
            }
        }
        __syncthreads();
    }

    // ---- acc -> sOut (+Eb), accb -> sBias (+web) ----
    float* sOut  = (float*)smem;
    float* sBias = (float*)(smem + SBIAS_OFF);
    const int lr4 = (lane >> 4) * 4;
    const int lc  = lane & 15;
    #pragma unroll
    for (int otl = 0; otl < 4; otl++) {
        int o = (wid * 4 + otl) * 16 + lc;
        int hh = o >> 5, col = o & 31;
        float ebv = Eb[o];
        #pragma unroll
        for (int g = 0; g < 4; g++) {
            int e = 16 * g + lr4;
            #pragma unroll
            for (int jr = 0; jr < 4; jr++)
                sOut[(e + jr) * SO_S + hh * SH_S + col] = acc[g][otl][jr] + ebv;
        }
    }
    if (wid == 0 && lc < 8) {
        float webv = web[lc];
        #pragma unroll
        for (int g = 0; g < 4; g++) {
            int e = 16 * g + lr4;
            #pragma unroll
            for (int jr = 0; jr < 4; jr++)
                sBias[(e + jr) * 12 + lc] = accb[g][jr] + webv;
        }
    }
    __syncthreads();

    // ---- per-edge epilogue ----
    const int hp = t & 3;
    const int ge = eb0 + e_l;
    if (ge < NE) {
        const float4* K4 = (const float4*)(Kh + (size_t)sIdx * 128);
        const float4* Q4 = (const float4*)(Qh + (size_t)dIdx * 128);
        const float inv_s4  = 0.5f;
        const float inv_s12 = 0.28867513459481288f;
        #pragma unroll
        for (int hi = 0; hi < 2; hi++) {
            int hh = 2 * hp + hi;
            float eb = sBias[e_l * 12 + hh];
            float4 kf[4], qf[4];
            #pragma unroll
            for (int j = 0; j < 4; j++) { kf[j] = K4[hh * 4 + j]; qf[j] = Q4[hh * 4 + j]; }
            float sem = kf[0].x*qf[0].x + kf[0].y*qf[0].y + kf[0].z*qf[0].z + kf[0].w*qf[0].w;
            float stl = 0.0f;
            #pragma unroll
            for (int j = 1; j < 4; j++)
                stl += kf[j].x*qf[j].x + kf[j].y*qf[j].y + kf[j].z*qf[j].z + kf[j].w*qf[j].w;
            float logit = sem * inv_s4 + stl * inv_s12 + eb;
            logit = fminf(fmaxf(logit, -CLAMP), CLAMP);
            float ex = __expf(logit);
            exOut[(size_t)ge * 8 + hh] = ex;
            const float* srow = sOut + e_l * SO_S + hh * SH_S;
            #pragma unroll
            for (int u = 0; u < 4; u++) {
                float4 A = *(const float4*)(srow + 4 * u);
                float4 B = *(const float4*)(srow + 16 + 4 * u);
                float4 kq = make_float4(kf[u].x + qf[u].x, kf[u].y + qf[u].y,
                                        kf[u].z + qf[u].z, kf[u].w + qf[u].w);
                float4 o;
                float v;
                v = kq.x * A.x; o.x = copysignf(sqrtf(fabsf(v)), v) + B.x;
                v = kq.y * A.y; o.y = copysignf(sqrtf(fabsf(v)), v) + B.y;
                v = kq.z * A.z; o.z = copysignf(sqrtf(fabsf(v)), v) + B.z;
                v = kq.w * A.w; o.w = copysignf(sqrtf(fabsf(v)), v) + B.w;
                *(float4*)(wE + (size_t)ge * 128 + hh * 16 + 4 * u) = o;
            }
        }
    }
}

// ---------------------------------------------------------------------------
// CSR build (unchanged)
// ---------------------------------------------------------------------------
__global__ __launch_bounds__(256) void count_kernel(
    const int* __restrict__ dstI, int* __restrict__ cnt)
{
    int e = blockIdx.x * 256 + threadIdx.x;
    if (e < NE) atomicAdd(&cnt[dstI[e]], 1);
}

__global__ __launch_bounds__(1024) void block_scan_kernel(
    const int* __restrict__ cnt, int* __restrict__ rowstart, int* __restrict__ bsum)
{
    __shared__ int sbuf[1024];
    const int b = blockIdx.x, t = threadIdx.x;
    const int i = b * 1024 + t;
    sbuf[t] = (i < N) ? cnt[i] : 0;
    __syncthreads();
    for (int off = 1; off < 1024; off <<= 1) {
        int xv = sbuf[t];
        int yv = (t >= off) ? sbuf[t - off] : 0;
        __syncthreads();
        sbuf[t] = xv + yv;
        __syncthreads();
    }
    if (i < N) rowstart[i + 1] = sbuf[t];
    if (t == 1023) bsum[b] = sbuf[1023];
}

__global__ void scan_totals_kernel(int* __restrict__ bsum, int nb)
{
    if (threadIdx.x == 0 && blockIdx.x == 0) {
        int run = 0;
        for (int b = 0; b < nb; b++) { int v = bsum[b]; bsum[b] = run; run += v; }
    }
}

__global__ __launch_bounds__(1024) void add_offsets_kernel(
    const int* __restrict__ bsum, int* __restrict__ rowstart)
{
    const int b = blockIdx.x, t = threadIdx.x;
    const int i = b * 1024 + t;
    if (i < N) rowstart[i + 1] += bsum[b];
    if (b == 0 && t == 0) rowstart[0] = 0;
}

__global__ __launch_bounds__(256) void scatter_kernel(
    const int* __restrict__ dstI, const int* __restrict__ rowstart,
    int* __restrict__ cursor, int* __restrict__ elist)
{
    int e = blockIdx.x * 256 + threadIdx.x;
    if (e >= NE) return;
    int d = dstI[e];
    int pos = atomicAdd(&cursor[d], 1);
    elist[rowstart[d] + pos] = e;
}

// ---------------------------------------------------------------------------
// K3: gather-based wV (unroll-2 for gather-latency overlap)
// ---------------------------------------------------------------------------
__global__ __launch_bounds__(256) void wv_kernel(
    const int* __restrict__ srcI, const int* __restrict__ elist,
    const int* __restrict__ rowstart, const float* __restrict__ Vh,
    const float* __restrict__ exOut, float* __restrict__ wV)
{
    const int dd = blockIdx.x * 2 + (threadIdx.x >> 7);
    const int o  = threadIdx.x & 127;
    if (dd >= N) return;
    const int h  = o >> 4;
    const int st = rowstart[dd];
    const int en = rowstart[dd + 1];
    float den = 0.0f, num = 0.0f;
    int i = st;
    for (; i + 2 <= en; i += 2) {
        int e0 = elist[i], e1 = elist[i + 1];
        int s0 = srcI[e0], s1 = srcI[e1];
        float ex0 = exOut[(size_t)e0 * 8 + h];
        float ex1 = exOut[(size_t)e1 * 8 + h];
        float v0 = Vh[(size_t)s0 * 128 + o];
        float v1 = Vh[(size_t)s1 * 128 + o];
        num = fmaf(v0, ex0, num);
        num = fmaf(v1, ex1, num);
        den += ex0 + ex1;
    }
    if (i < en) {
        int e0 = elist[i];
        int s0 = srcI[e0];
        float ex0 = exOut[(size_t)e0 * 8 + h];
        num = fmaf(Vh[(size_t)s0 * 128 + o], ex0, num);
        den += ex0;
    }
    wV[(size_t)dd * 128 + o] = num / (den + 1e-16f);
}

// ---------------------------------------------------------------------------
extern "C" void kernel_launch(void* const* d_in, const int* in_sizes, int n_in,
                              void* d_out, int out_size, void* d_ws, size_t ws_size,
                              hipStream_t stream)
{
    const float* x         = (const float*)d_in[0];
    const int*   edge_idx  = (const int*)d_in[1];
    const float* rrwp      = (const float*)d_in[2];
    const float* edge_attr = (const float*)d_in[3];
    const float* Qw        = (const float*)d_in[4];
    const float* Qb        = (const float*)d_in[5];
    const float* Kw        = (const float*)d_in[6];
    const float* Kb        = (const float*)d_in[7];
    const float* Vw        = (const float*)d_in[8];
    const float* Vb        = (const float*)d_in[9];
    const float* Ew        = (const float*)d_in[10];
    const float* Eb        = (const float*)d_in[11];
    const float* wew       = (const float*)d_in[12];
    const float* web       = (const float*)d_in[13];
    const float* Wang      = (const float*)d_in[14];

    const int* srcI = edge_idx;
    const int* dstI = edge_idx + NE;

    float* wV = (float*)d_out;                       // N * 128
    float* wE = wV + (size_t)N * 128;                // NE * 128

    // workspace layout
    ushort* EwHiF = (ushort*)d_ws;                   // 17*2048 = 34816 bf16
    ushort* EwLoF = EwHiF + 34816;                   // 34816
    ushort* QWHiF = EwLoF + 34816;                   // 49152
    ushort* QWLoF = QWHiF + 49152;                   // 49152
    float* Qh   = (float*)(QWLoF + 49152);
    float* Kh   = Qh + (size_t)N * 128;
    float* Vh   = Kh + (size_t)N * 128;
    float* exO  = Vh + (size_t)N * 128;              // NE*8
    int* cnt      = (int*)(exO + (size_t)NE * 8);    // N
    int* rowstart = cnt + N;                         // N+1
    int* cursor   = rowstart + (N + 1);              // N
    int* elist    = cursor + N;                      // NE
    int* bsum     = elist + NE;                      // 64

    const int NB_SCAN = (N + 1023) / 1024;           // 49

    hipMemsetAsync(cnt, 0, (size_t)N * sizeof(int), stream);
    hipMemsetAsync(cursor, 0, (size_t)N * sizeof(int), stream);

    prep_w_kernel<<<17, 256, 0, stream>>>(Ew, wew, EwHiF, EwLoF);
    prep_qkvw_kernel<<<24, 256, 0, stream>>>(Qw, Kw, Vw, QWHiF, QWLoF);

    qkv_mfma_kernel<<<(N + 63) / 64, 256, 0, stream>>>(
        x, rrwp, QWHiF, QWLoF, Qb, Kb, Vb, Wang, Qh, Kh, Vh);

    count_kernel<<<(NE + 255) / 256, 256, 0, stream>>>(dstI, cnt);
    block_scan_kernel<<<NB_SCAN, 1024, 0, stream>>>(cnt, rowstart, bsum);
    scan_totals_kernel<<<1, 64, 0, stream>>>(bsum, NB_SCAN);
    add_offsets_kernel<<<NB_SCAN, 1024, 0, stream>>>(bsum, rowstart);
    scatter_kernel<<<(NE + 255) / 256, 256, 0, stream>>>(dstI, rowstart, cursor, elist);

    edge_gemm_kernel<<<(NE + 63) / 64, 256, 0, stream>>>(
        edge_attr, srcI, dstI, Qh, Kh, EwHiF, EwLoF, Eb, web, wE, exO);

    wv_kernel<<<(N + 1) / 2, 256, 0, stream>>>(
        srcI, elist, rowstart, Vh, exO, wV);
}